// Round 11
// baseline (18381.589 us; speedup 1.0000x reference)
//
#include <hip/hip_runtime.h>
#include <stdint.h>

// Qwen3 decoder, 28L, Q=512, D=1024, HQ=16, HKV=8, HD=128, DFF=3072.
// R11: persistent mega-kernel (512 blocks) with FIXED grid barrier:
// monotonic tree barrier (64 padded leaves -> root -> gen on separate lines),
// static conv-tile assignment (no work-steal atomics). Phase jobs and the
// 3-deep-prefetch GEMM loop are the proven R7/R8 versions. 4 launches.

typedef __bf16 bf16_t;
typedef _Float16 f16_t;
typedef __bf16 bf16x8 __attribute__((ext_vector_type(8)));
typedef __bf16 bf16x4 __attribute__((ext_vector_type(4)));
typedef _Float16 f16x8 __attribute__((ext_vector_type(8)));
typedef float f32x4 __attribute__((ext_vector_type(4)));

#define SEQ 512
#define HD 128
#define NBLK 512

#define IMG_QKV 0ull
#define IMG_WO  8388608ull
#define IMG_GU  12582912ull
#define IMG_WD  25165824ull
#define IMG_LAYER_BYTES 31457280ull

typedef const __attribute__((address_space(1))) uint32_t as1_u32;
typedef __attribute__((address_space(3))) uint32_t as3_u32;

__device__ __forceinline__ void gload16(const void* g, void* l) {
    __builtin_amdgcn_global_load_lds((as1_u32*)g, (as3_u32*)l, 16, 0, 0);
}

#define WAITV12 asm volatile("s_waitcnt vmcnt(12)" ::: "memory")
#define WAITV6  asm volatile("s_waitcnt vmcnt(6)" ::: "memory")
#define WAITV0  asm volatile("s_waitcnt vmcnt(0)" ::: "memory")

__device__ __forceinline__ size_t aoff(int row, int col, int ldak) {
    return (((size_t)((row >> 6) * ldak + (col >> 6))) << 13) +
           ((size_t)(row & 63) << 7) +
           (size_t)((((col & 63) << 1)) ^ ((row & 7) << 4));
}

// ---------------------------------------------------------------------------
// monotonic tree grid-barrier.
// sync layout (u32 idx): leaf l at l*32 (128B stride, 64 leaves);
// root at 2048; gen at 2560. All on separate cache lines / pages.
__device__ __forceinline__ void gbar(uint32_t* sync, uint32_t ep) {
    __syncthreads();
    if (threadIdx.x == 0) {
        __threadfence();
        uint32_t* leaf = sync + ((blockIdx.x >> 3) << 5);
        uint32_t a = __hip_atomic_fetch_add(leaf, 1u, __ATOMIC_ACQ_REL,
                                            __HIP_MEMORY_SCOPE_AGENT);
        if ((a & 7u) == 7u) {
            uint32_t r = __hip_atomic_fetch_add(sync + 2048, 1u, __ATOMIC_ACQ_REL,
                                                __HIP_MEMORY_SCOPE_AGENT);
            if ((r & 63u) == 63u)
                __hip_atomic_store(sync + 2560, ep, __ATOMIC_RELEASE,
                                   __HIP_MEMORY_SCOPE_AGENT);
        }
        while (__hip_atomic_load(sync + 2560, __ATOMIC_ACQUIRE,
                                 __HIP_MEMORY_SCOPE_AGENT) < ep)
            __builtin_amdgcn_s_sleep(2);
    }
    __syncthreads();
}

// ---------------------------------------------------------------------------
__global__ __launch_bounds__(256) void k_init(uint32_t* sync) {
#pragma unroll
    for (int i = 0; i < 12; ++i) sync[i * 256 + threadIdx.x] = 0;
}

__global__ __launch_bounds__(256) void k_copy(const float* __restrict__ src,
                                              float* __restrict__ dst)
{
    size_t i = ((size_t)blockIdx.x * 256 + threadIdx.x) * 4;
    *(float4*)(dst + i) = *(const float4*)(src + i);
}

// ---------------------------------------------------------------------------
// weight tile convert: one 64x64 tile, b in [0,3840)
__device__ __forceinline__ void conv_tile(
    int b, int lay,
    const float* __restrict__ Wq, const float* __restrict__ Wk,
    const float* __restrict__ Wv, const float* __restrict__ Wo,
    const float* __restrict__ Wg, const float* __restrict__ Wu,
    const float* __restrict__ Wd, char* __restrict__ ib, void* smemv)
{
    const float* wq = Wq + (size_t)lay * 1024 * 2048;
    const float* wk = Wk + (size_t)lay * 1024 * 1024;
    const float* wv = Wv + (size_t)lay * 1024 * 1024;
    const float* wo = Wo + (size_t)lay * 2048 * 1024;
    const float* wg = Wg + (size_t)lay * 1024 * 3072;
    const float* wu = Wu + (size_t)lay * 1024 * 3072;
    const float* wd = Wd + (size_t)lay * 3072 * 1024;

    const float* src = nullptr;
    int ldbw = 0, n, kt, guMode = 0;
    size_t dstoff;
    if (b < 1024) {
        n = b >> 4; kt = b & 15;
        int C0 = n * 64;
        if (C0 < 2048)      { src = wq + C0;          ldbw = 2048; }
        else if (C0 < 3072) { src = wk + (C0 - 2048); ldbw = 1024; }
        else                { src = wv + (C0 - 3072); ldbw = 1024; }
        src += (size_t)(kt * 64) * ldbw;
        dstoff = IMG_QKV + (size_t)b * 8192;
    } else if (b < 1536) {
        int b2 = b - 1024; n = b2 >> 5; kt = b2 & 31;
        src = wo + (size_t)(kt * 64) * 1024 + n * 64; ldbw = 1024;
        dstoff = IMG_WO + (size_t)b2 * 8192;
    } else if (b < 3072) {
        int b3 = b - 1536; n = b3 >> 4; kt = b3 & 15;
        guMode = 1; ldbw = 3072;
        dstoff = IMG_GU + (size_t)b3 * 8192;
    } else {
        int b4 = b - 3072; n = b4 / 48; kt = b4 % 48;
        src = wd + (size_t)(kt * 64) * 1024 + n * 64; ldbw = 1024;
        dstoff = IMG_WD + (size_t)b4 * 8192;
    }

    float (*T)[68] = (float (*)[68])smemv;
    int tid = threadIdx.x;
    if (!guMode) {
#pragma unroll
        for (int it = 0; it < 4; ++it) {
            int idx = it * 256 + tid;
            int kk = idx >> 4, seg = idx & 15;
            *(float4*)&T[kk][seg * 4] = *(const float4*)(src + (size_t)kk * ldbw + seg * 4);
        }
    } else {
        const float* wg_ = wg + (size_t)(kt * 64) * 3072;
        const float* wu_ = wu + (size_t)(kt * 64) * 3072;
#pragma unroll
        for (int it = 0; it < 4; ++it) {
            int idx = it * 256 + tid;
            int kk = idx >> 4, seg = idx & 15;
            int nl = seg * 4;
            int colc = n * 32 + ((nl >> 5) & 1) * 16 + (nl & 15);
            const float* s2 = (((nl >> 4) & 1) ? wu_ : wg_) + (size_t)kk * 3072 + colc;
            *(float4*)&T[kk][nl] = *(const float4*)s2;
        }
    }
    __syncthreads();
    char* dst = ib + dstoff;
#pragma unroll
    for (int it = 0; it < 2; ++it) {
        int kg = tid & 7;
        int nrow = it * 32 + (tid >> 3);
        bf16x8 o;
#pragma unroll
        for (int j = 0; j < 8; ++j) o[j] = (bf16_t)T[kg * 8 + j][nrow];
        *(bf16x8*)(dst + nrow * 128 + ((kg * 16) ^ ((nrow & 7) << 4))) = o;
    }
}

__global__ __launch_bounds__(256) void k_conv(
    int lay,
    const float* __restrict__ Wq, const float* __restrict__ Wk,
    const float* __restrict__ Wv, const float* __restrict__ Wo,
    const float* __restrict__ Wg, const float* __restrict__ Wu,
    const float* __restrict__ Wd, char* __restrict__ img)
{
    __shared__ __align__(16) char smem[17408];
    conv_tile(blockIdx.x, lay, Wq, Wk, Wv, Wo, Wg, Wu, Wd, img, smem);
}

// ---------------------------------------------------------------------------
// residual(+4 bf16 partials) + RMSNorm -> image row t
__device__ __forceinline__ void rms_job(
    int t, float* __restrict__ h, const bf16_t* __restrict__ parts, int nparts,
    const float* __restrict__ w, char* __restrict__ ximg)
{
    int tid = threadIdx.x;
    size_t base = (size_t)t * 1024 + tid * 4;
    float4 v = *(const float4*)(h + base);
    for (int p = 0; p < nparts; ++p) {
        bf16x4 a = *(const bf16x4*)(parts + (size_t)p * 524288 + base);
        v.x += (float)a[0]; v.y += (float)a[1]; v.z += (float)a[2]; v.w += (float)a[3];
    }
    if (nparts) *(float4*)(h + base) = v;
    float ss = v.x * v.x + v.y * v.y + v.z * v.z + v.w * v.w;
#pragma unroll
    for (int m = 1; m < 64; m <<= 1) ss += __shfl_xor(ss, m);
    __shared__ float red[4];
    if ((tid & 63) == 0) red[tid >> 6] = ss;
    __syncthreads();
    float tot = (red[0] + red[1]) + (red[2] + red[3]);
    float sc = rsqrtf(tot * (1.0f / 1024.0f) + 1e-6f);
    float4 wv4 = *(const float4*)(w + tid * 4);
    bf16x4 o;
    o[0] = (bf16_t)(v.x * sc * wv4.x);
    o[1] = (bf16_t)(v.y * sc * wv4.y);
    o[2] = (bf16_t)(v.z * sc * wv4.z);
    o[3] = (bf16_t)(v.w * sc * wv4.w);
    *(bf16x4*)(ximg + aoff(t, tid * 4, 16)) = o;
    __syncthreads();
}

// ---------------------------------------------------------------------------
// GEMM main loop: BM=64, BN=128, BK=64; 4 waves (2x2), 32x64 per wave.
// 3-deep prefetch: stage(t+2); vmcnt(12); barrier; compute(t); barrier.
template <int NBN, int SPLITK, int LDAK>
__device__ __forceinline__ void gemm_loop(
    const char* __restrict__ Aimg, const char* __restrict__ Bimg,
    char* smem, int f, f32x4 (&acc)[2][4], int& bmO, int& bnO, int& sO)
{
    const int steps = LDAK / SPLITK;
    int bm = f / (NBN * SPLITK);
    int r = f % (NBN * SPLITK);
    int s = r / NBN;
    int bn = r % NBN;
    int k0d = s * steps;
    bmO = bm; bnO = bn; sO = s;

    int tid = threadIdx.x;
    int wv = tid >> 6, l = tid & 63, lg = l >> 4, lr = l & 15;
    int wr = wv >> 1, wc = wv & 1;

#pragma unroll
    for (int i = 0; i < 2; ++i)
#pragma unroll
        for (int j = 0; j < 4; ++j) { f32x4 z = {0.f, 0.f, 0.f, 0.f}; acc[i][j] = z; }

    auto stage = [&](int buf, int kt) {
        const char* ab = Aimg + ((size_t)(bm * LDAK + k0d + kt)) * 8192;
        const char* b0 = Bimg + ((size_t)((2 * bn) * LDAK + k0d + kt)) * 8192;
        const char* b1 = Bimg + ((size_t)((2 * bn + 1) * LDAK + k0d + kt)) * 8192;
        char* al = smem + buf * 24576;
        char* bl = al + 8192;
#pragma unroll
        for (int u = 0; u < 2; ++u) {
            int off = (wv * 2 + u) * 1024;
            gload16(ab + off + l * 16, al + off);
        }
#pragma unroll
        for (int u = 0; u < 4; ++u) {
            int off = (wv * 4 + u) * 1024;
            const char* src = (off < 8192) ? (b0 + off) : (b1 + off - 8192);
            gload16(src + l * 16, bl + off);
        }
    };
    auto compute = [&](int buf) {
        const char* as = smem + buf * 24576;
        const char* bs = as + 8192 + wc * 8192;
        __builtin_amdgcn_s_setprio(1);
#pragma unroll
        for (int c = 0; c < 2; ++c) {
            int co = (c * 64 + lg * 16) ^ ((lr & 7) << 4);
            bf16x8 af[2], bf[4];
#pragma unroll
            for (int i = 0; i < 2; ++i)
                af[i] = *(const bf16x8*)(as + (wr * 32 + i * 16 + lr) * 128 + co);
#pragma unroll
            for (int j = 0; j < 4; ++j)
                bf[j] = *(const bf16x8*)(bs + (j * 16 + lr) * 128 + co);
#pragma unroll
            for (int i = 0; i < 2; ++i)
#pragma unroll
                for (int j = 0; j < 4; ++j)
                    acc[i][j] = __builtin_amdgcn_mfma_f32_16x16x32_bf16(
                        af[i], bf[j], acc[i][j], 0, 0, 0);
        }
        __builtin_amdgcn_s_setprio(0);
    };

    stage(0, 0);
    stage(1, 1);
    int buf = 0;
    for (int kt = 0; kt < steps; ++kt) {
        if (kt + 2 < steps)      { stage((kt + 2) % 3, kt + 2); WAITV12; }
        else if (kt + 1 < steps) { WAITV6; }
        else                     { WAITV0; }
        __builtin_amdgcn_sched_barrier(0);
        __builtin_amdgcn_s_barrier();
        __builtin_amdgcn_sched_barrier(0);
        compute(buf);
        __builtin_amdgcn_s_barrier();
        buf = (buf == 2) ? 0 : buf + 1;
    }
}

// ---------------------------------------------------------------------------
// qkv GEMM job + fused q/k rmsnorm+rope / v-transpose epilogue
__device__ __forceinline__ void qkv_job(
    int f, const char* __restrict__ Aimg, const char* __restrict__ Bimg,
    const float* __restrict__ cosb, const float* __restrict__ sinb,
    const float* __restrict__ qw, const float* __restrict__ kw,
    f16_t* __restrict__ qf, f16_t* __restrict__ kf, f16_t* __restrict__ vT,
    char* smem)
{
    f32x4 acc[2][4];
    int bm, bn, s;
    gemm_loop<32, 1, 16>(Aimg, Bimg, smem, f, acc, bm, bn, s);

    int tid = threadIdx.x;
    int wv = tid >> 6, l = tid & 63, lg = l >> 4, lr = l & 15;
    int wr = wv >> 1, wc = wv & 1;
    float (*X)[132] = (float (*)[132])smem;
    __syncthreads();
#pragma unroll
    for (int i = 0; i < 2; ++i)
#pragma unroll
        for (int j = 0; j < 4; ++j)
#pragma unroll
            for (int ii = 0; ii < 4; ++ii)
                X[wr * 32 + i * 16 + lg * 4 + ii][wc * 64 + j * 16 + lr] = acc[i][j][ii];
    __syncthreads();

    int t0 = bm * 64;
    if (bn < 24) {
        bool isq = bn < 16;
        int slot = isq ? bn : bn - 16;
        const float* wn = isq ? qw : kw;
        int r = tid >> 2, part = tid & 3;
        float ss = 0.f;
#pragma unroll
        for (int c = 0; c < 32; ++c) { float v = X[r][part * 32 + c]; ss += v * v; }
        ss += __shfl_xor(ss, 1);
        ss += __shfl_xor(ss, 2);
        float sc = rsqrtf(ss * (1.0f / 128.0f) + 1e-6f);
        int t = t0 + r;
        int d0 = part * 16;
        float o1v[16], o2v[16];
#pragma unroll
        for (int c = 0; c < 16; ++c) {
            int d = d0 + c;
            float xv1 = X[r][d] * sc * wn[d];
            float xv2 = X[r][d + 64] * sc * wn[d + 64];
            o1v[c] = xv1 * cosb[t * HD + d] - xv2 * sinb[t * HD + d];
            o2v[c] = xv2 * cosb[t * HD + d + 64] + xv1 * sinb[t * HD + d + 64];
        }
        f16x8 w0, w1, w2, w3;
#pragma unroll
        for (int c = 0; c < 8; ++c) {
            w0[c] = (f16_t)o1v[c];     w1[c] = (f16_t)o1v[8 + c];
            w2[c] = (f16_t)o2v[c];     w3[c] = (f16_t)o2v[8 + c];
        }
        f16_t* o = (isq ? qf : kf) + ((size_t)slot * SEQ + t) * HD;
        *(f16x8*)(o + d0) = w0;
        *(f16x8*)(o + d0 + 8) = w1;
        *(f16x8*)(o + d0 + 64) = w2;
        *(f16x8*)(o + d0 + 72) = w3;
    } else {
        int kvh = bn - 24;
#pragma unroll
        for (int it = 0; it < 4; ++it) {
            int task = it * 256 + tid;
            int d = task >> 3, seg = task & 7;
            f16x8 o;
#pragma unroll
            for (int j = 0; j < 8; ++j) o[j] = (f16_t)X[seg * 8 + j][d];
            *(f16x8*)(vT + ((size_t)kvh * HD + d) * SEQ + t0 + seg * 8) = o;
        }
    }
    __syncthreads();
}

// ---------------------------------------------------------------------------
// split-K GEMM job -> bf16 partials (wo / wd)
template <int LDAK>
__device__ __forceinline__ void part_job(
    int f, const char* A, const char* B, bf16_t* parts, char* smem)
{
    f32x4 acc[2][4];
    int bm, bn, s;
    gemm_loop<8, 4, LDAK>(A, B, smem, f, acc, bm, bn, s);
    int tid = threadIdx.x;
    int wv = tid >> 6, l = tid & 63, lg = l >> 4, lr = l & 15;
    int wr = wv >> 1, wc = wv & 1;
    bf16_t* P = parts + (size_t)s * 524288;
#pragma unroll
    for (int i = 0; i < 2; ++i)
#pragma unroll
        for (int j = 0; j < 4; ++j)
#pragma unroll
            for (int ii = 0; ii < 4; ++ii) {
                int row = bm * 64 + wr * 32 + i * 16 + lg * 4 + ii;
                int col = bn * 128 + wc * 64 + j * 16 + lr;
                P[(size_t)row * 1024 + col] = (bf16_t)acc[i][j][ii];
            }
    __syncthreads();
}

// gu GEMM job + fused swiglu -> mimg
__device__ __forceinline__ void gu_job(
    int f, const char* A, const char* B, char* mimg, char* smem)
{
    f32x4 acc[2][4];
    int bm, bn, s;
    gemm_loop<48, 1, 16>(A, B, smem, f, acc, bm, bn, s);
    int tid = threadIdx.x;
    int wv = tid >> 6, l = tid & 63, lg = l >> 4, lr = l & 15;
    int wr = wv >> 1, wc = wv & 1;
#pragma unroll
    for (int i = 0; i < 2; ++i)
#pragma unroll
        for (int jp = 0; jp < 2; ++jp)
#pragma unroll
            for (int ii = 0; ii < 4; ++ii) {
                int row = bm * 64 + wr * 32 + i * 16 + lg * 4 + ii;
                int col = (bn * 2 + wc) * 32 + jp * 16 + lr;
                float gv = acc[i][2 * jp][ii];
                float uv = acc[i][2 * jp + 1][ii];
                float val = gv / (1.f + __expf(-gv)) * uv;
                *(bf16_t*)(mimg + aoff(row, col, 48)) = (bf16_t)val;
            }
    __syncthreads();
}

// ---------------------------------------------------------------------------
// flash attention job: 4 waves, 64 q-rows. job = h*8 + qb (128 jobs)
__device__ __forceinline__ void attn_job(
    int job, const f16_t* __restrict__ qf, const f16_t* __restrict__ kf,
    const f16_t* __restrict__ vT, char* __restrict__ attimg, char* smem)
{
    int h = job >> 3, qb = job & 7;
    int kvh = h >> 1;
    f16_t (*Kt)[136] = (f16_t (*)[136])smem;
    f16_t (*Vt)[72]  = (f16_t (*)[72])(smem + 17408);
    f16_t (*Pl)[16][72] = (f16_t (*)[16][72])(smem + 35840);
    int tid = threadIdx.x;
    int wv = tid >> 6, l = tid & 63, lg = l >> 4, lr = l & 15;
    int qrow = qb * 64 + wv * 16;

    f16x8 aq[4];
    const f16_t* qp = qf + ((size_t)h * SEQ + qrow + lr) * HD;
#pragma unroll
    for (int c = 0; c < 4; ++c) aq[c] = *(const f16x8*)(qp + c * 32 + lg * 8);

    f32x4 accv[8];
#pragma unroll
    for (int df = 0; df < 8; ++df) { f32x4 z = {0.f, 0.f, 0.f, 0.f}; accv[df] = z; }
    float mrun[4], lrun[4];
#pragma unroll
    for (int ii = 0; ii < 4; ++ii) { mrun[ii] = -3e38f; lrun[ii] = 0.f; }

    int ktiles = qb + 1;
    for (int kt = 0; kt < ktiles; ++kt) {
        int kt0 = kt * 64;
        __syncthreads();
#pragma unroll
        for (int it = 0; it < 4; ++it) {
            int idx = it * 256 + tid;
            int r = idx >> 4, seg = idx & 15;
            *(int4*)&Kt[r][seg * 8] =
                *(const int4*)(kf + ((size_t)kvh * SEQ + kt0 + r) * HD + seg * 8);
        }
#pragma unroll
        for (int it = 0; it < 4; ++it) {
            int idx = it * 256 + tid;
            int r = idx >> 3, seg = idx & 7;
            *(int4*)&Vt[r][seg * 8] =
                *(const int4*)(vT + ((size_t)kvh * HD + r) * SEQ + kt0 + seg * 8);
        }
        __syncthreads();

        f32x4 s[4];
#pragma unroll
        for (int nf = 0; nf < 4; ++nf) {
            f32x4 a = {0.f, 0.f, 0.f, 0.f};
#pragma unroll
            for (int c = 0; c < 4; ++c) {
                f16x8 bk = *(const f16x8*)&Kt[nf * 16 + lr][c * 32 + lg * 8];
                a = __builtin_amdgcn_mfma_f32_16x16x32_f16(aq[c], bk, a, 0, 0, 0);
            }
            s[nf] = a;
        }
        const float scale = 0.08838834764831845f;
        float tmax[4] = {-3e38f, -3e38f, -3e38f, -3e38f};
#pragma unroll
        for (int nf = 0; nf < 4; ++nf) {
            int ktg = kt0 + nf * 16 + lr;
#pragma unroll
            for (int ii = 0; ii < 4; ++ii) {
                int qg = qrow + lg * 4 + ii;
                float vv = s[nf][ii] * scale;
                vv = (ktg <= qg) ? vv : -1e30f;
                s[nf][ii] = vv;
                tmax[ii] = fmaxf(tmax[ii], vv);
            }
        }
#pragma unroll
        for (int m = 1; m < 16; m <<= 1)
#pragma unroll
            for (int ii = 0; ii < 4; ++ii)
                tmax[ii] = fmaxf(tmax[ii], __shfl_xor(tmax[ii], m));
        float corr[4];
#pragma unroll
        for (int ii = 0; ii < 4; ++ii) {
            float mnew = fmaxf(mrun[ii], tmax[ii]);
            corr[ii] = __expf(mrun[ii] - mnew);
            mrun[ii] = mnew;
        }
        float tsum[4] = {0.f, 0.f, 0.f, 0.f};
#pragma unroll
        for (int nf = 0; nf < 4; ++nf)
#pragma unroll
            for (int ii = 0; ii < 4; ++ii) {
                float pp = __expf(s[nf][ii] - mrun[ii]);
                s[nf][ii] = pp;
                tsum[ii] += pp;
            }
#pragma unroll
        for (int m = 1; m < 16; m <<= 1)
#pragma unroll
            for (int ii = 0; ii < 4; ++ii) tsum[ii] += __shfl_xor(tsum[ii], m);
#pragma unroll
        for (int ii = 0; ii < 4; ++ii) lrun[ii] = lrun[ii] * corr[ii] + tsum[ii];
#pragma unroll
        for (int df = 0; df < 8; ++df)
#pragma unroll
            for (int ii = 0; ii < 4; ++ii) accv[df][ii] *= corr[ii];
#pragma unroll
        for (int nf = 0; nf < 4; ++nf)
#pragma unroll
            for (int ii = 0; ii < 4; ++ii)
                Pl[wv][lg * 4 + ii][nf * 16 + lr] = (f16_t)s[nf][ii];
        __syncthreads();
#pragma unroll
        for (int c = 0; c < 2; ++c) {
            f16x8 ap = *(const f16x8*)&Pl[wv][lr][c * 32 + lg * 8];
#pragma unroll
            for (int df = 0; df < 8; ++df) {
                f16x8 bv = *(const f16x8*)&Vt[df * 16 + lr][c * 32 + lg * 8];
                accv[df] = __builtin_amdgcn_mfma_f32_16x16x32_f16(ap, bv, accv[df], 0, 0, 0);
            }
        }
    }
#pragma unroll
    for (int df = 0; df < 8; ++df)
#pragma unroll
        for (int ii = 0; ii < 4; ++ii) {
            int qg = qrow + lg * 4 + ii;
            int col = h * HD + df * 16 + lr;
            *(bf16_t*)(attimg + aoff(qg, col, 32)) =
                (bf16_t)(accv[df][ii] / lrun[ii]);
        }
    __syncthreads();
}

// ---------------------------------------------------------------------------
// the mega kernel: 512 blocks, 2 blocks/CU guaranteed (LDS 72KB x2 <= 160KB)
__global__ __launch_bounds__(256, 2) void k_mega(
    float* __restrict__ h, bf16_t* __restrict__ parts,
    char* __restrict__ ximg, char* __restrict__ yimg,
    char* __restrict__ attimg, char* __restrict__ mimg,
    f16_t* __restrict__ qf, f16_t* __restrict__ kf, f16_t* __restrict__ vT,
    char* __restrict__ imgA, char* __restrict__ imgB,
    const float* __restrict__ cosb, const float* __restrict__ sinb,
    const float* __restrict__ Wq, const float* __restrict__ Wk,
    const float* __restrict__ Wv, const float* __restrict__ Wo,
    const float* __restrict__ Wg, const float* __restrict__ Wu,
    const float* __restrict__ Wd,
    const float* __restrict__ Ln1, const float* __restrict__ Ln2,
    const float* __restrict__ Qn, const float* __restrict__ Kn,
    uint32_t* __restrict__ sync, float* __restrict__ out)
{
    __shared__ __align__(128) char smem[73728];
    const int b = blockIdx.x;
    const int tid = threadIdx.x;
    uint32_t ep = 0;

    // static conv: slot handles tiles [base+slot*3, base+slot*3+3) of layer l+1
    auto conv3 = [&](int slot, int base, int lnext, char* imgn) {
        int t0 = base + slot * 3;
#pragma unroll 1
        for (int t = 0; t < 3; ++t) {
            conv_tile(t0 + t, lnext, Wq, Wk, Wv, Wo, Wg, Wu, Wd, imgn, smem);
            __syncthreads();
        }
    };

    for (int l = 0; l < 28; ++l) {
        const char* img = (l & 1) ? imgB : imgA;
        char* imgn = (l & 1) ? imgA : imgB;
        bool cv = (l < 27);
        int ln = l + 1;

        // P1: rms1 (512 rows)
        rms_job(b, h, parts, l == 0 ? 0 : 4, Ln1 + (size_t)l * 1024, ximg);
        ++ep; gbar(sync, ep);
        // P2: qkv (256) | conv tiles [0,768)
        if (b < 256) qkv_job(b, ximg, img + IMG_QKV, cosb, sinb,
                             Qn + (size_t)l * 128, Kn + (size_t)l * 128,
                             qf, kf, vT, smem);
        else if (cv) conv3(b - 256, 0, ln, imgn);
        ++ep; gbar(sync, ep);
        // P3: attention (128 jobs, 4-wave) | conv [768,1920)
        if (b < 128) attn_job(b, qf, kf, vT, attimg, smem);
        else if (cv) conv3(b - 128, 768, ln, imgn);
        ++ep; gbar(sync, ep);
        // P4: wo -> parts (256) | conv [1920,2688)
        if (b < 256) part_job<32>(b, attimg, img + IMG_WO, parts, smem);
        else if (cv) conv3(b - 256, 1920, ln, imgn);
        ++ep; gbar(sync, ep);
        // P5: rms2
        rms_job(b, h, parts, 4, Ln2 + (size_t)l * 1024, yimg);
        ++ep; gbar(sync, ep);
        // P6: gu (384 jobs) | conv [2688,3072)
        if (b < 384) gu_job(b, yimg, img + IMG_GU, mimg, smem);
        else if (cv) conv3(b - 384, 2688, ln, imgn);
        ++ep; gbar(sync, ep);
        // P7: wd -> parts (256) | conv [3072,3840)
        if (b < 256) part_job<48>(b, mimg, img + IMG_WD, parts, smem);
        else if (cv) conv3(b - 256, 3072, ln, imgn);
        ++ep; gbar(sync, ep);
    }
    // finalize: out = h + partials, row b
    {
        size_t base = (size_t)b * 1024 + tid * 4;
        float4 v = *(const float4*)(h + base);
#pragma unroll
        for (int p = 0; p < 4; ++p) {
            bf16x4 a = *(const bf16x4*)(parts + (size_t)p * 524288 + base);
            v.x += (float)a[0]; v.y += (float)a[1]; v.z += (float)a[2]; v.w += (float)a[3];
        }
        *(float4*)(out + base) = v;
    }
}

// ---------------------------------------------------------------------------
extern "C" void kernel_launch(void* const* d_in, const int* in_sizes, int n_in,
                              void* d_out, int out_size, void* d_ws, size_t ws_size,
                              hipStream_t stream)
{
    const float* hin  = (const float*)d_in[0];
    const float* cosb = (const float*)d_in[1];
    const float* sinb = (const float*)d_in[2];
    const float* Wq = (const float*)d_in[4];
    const float* Wk = (const float*)d_in[5];
    const float* Wv = (const float*)d_in[6];
    const float* Wo = (const float*)d_in[7];
    const float* Wg = (const float*)d_in[8];
    const float* Wu = (const float*)d_in[9];
    const float* Wd = (const float*)d_in[10];
    const float* Ln1 = (const float*)d_in[11];
    const float* Ln2 = (const float*)d_in[12];
    const float* Qn = (const float*)d_in[13];
    const float* Kn = (const float*)d_in[14];

    char* p = (char*)d_ws;
    auto alloc = [&](size_t bytes) { char* r = p; p += bytes; return r; };
    float*  h     = (float*)alloc(2097152);
    bf16_t* parts = (bf16_t*)alloc(4194304);
    char*   ximg  = alloc(1048576);
    char*   yimg  = alloc(1048576);
    char*   attimg= alloc(2097152);
    char*   mimg  = alloc(3145728);
    f16_t*  qf    = (f16_t*)alloc(2097152);
    f16_t*  kf    = (f16_t*)alloc(1048576);
    f16_t*  vT    = (f16_t*)alloc(1048576);
    uint32_t* sync= (uint32_t*)alloc(16384);
    char*   imgA  = alloc(IMG_LAYER_BYTES);
    char*   imgB  = alloc(IMG_LAYER_BYTES);

    k_init<<<1, 256, 0, stream>>>(sync);
    k_copy<<<512, 256, 0, stream>>>(hin, h);
    k_conv<<<3840, 256, 0, stream>>>(0, Wq, Wk, Wv, Wo, Wg, Wu, Wd, imgA);
    k_mega<<<NBLK, 256, 0, stream>>>(h, parts, ximg, yimg, attimg, mimg,
                                     qf, kf, vT, imgA, imgB, cosb, sinb,
                                     Wq, Wk, Wv, Wo, Wg, Wu, Wd,
                                     Ln1, Ln2, Qn, Kn, sync, (float*)d_out);
}

// Round 12
// 8935.605 us; speedup vs baseline: 2.0571x; 2.0571x over previous
//
#include <hip/hip_runtime.h>
#include <stdint.h>

// Qwen3 decoder, 28L, Q=512, D=1024, HQ=16, HKV=8, HD=128, DFF=3072.
// R12 = R8 multi-kernel structure + stream-K "last-arriver fixup": wo/wd
// (split-K4 -> bf16 parts, unchanged GEMM) end with a per-bm arrival counter;
// the 32nd block sums parts + residual-adds h + RMSNorms + writes the next
// GEMM's A-image (or d_out on the last layer). k_rms x2 and k_finalize are
// gone: 5 kernels/layer, 143 launches.

typedef __bf16 bf16_t;
typedef _Float16 f16_t;
typedef __bf16 bf16x8 __attribute__((ext_vector_type(8)));
typedef __bf16 bf16x4 __attribute__((ext_vector_type(4)));
typedef _Float16 f16x8 __attribute__((ext_vector_type(8)));
typedef float f32x4 __attribute__((ext_vector_type(4)));

#define SEQ 512
#define HD 128

#define IMG_QKV 0ull
#define IMG_WO  8388608ull
#define IMG_GU  12582912ull
#define IMG_WD  25165824ull
#define IMG_LAYER_BYTES 31457280ull

typedef const __attribute__((address_space(1))) uint32_t as1_u32;
typedef __attribute__((address_space(3))) uint32_t as3_u32;

__device__ __forceinline__ void gload16(const void* g, void* l) {
    __builtin_amdgcn_global_load_lds((as1_u32*)g, (as3_u32*)l, 16, 0, 0);
}

#define WAITV12 asm volatile("s_waitcnt vmcnt(12)" ::: "memory")
#define WAITV6  asm volatile("s_waitcnt vmcnt(6)" ::: "memory")
#define WAITV0  asm volatile("s_waitcnt vmcnt(0)" ::: "memory")

__device__ __forceinline__ size_t aoff(int row, int col, int ldak) {
    return (((size_t)((row >> 6) * ldak + (col >> 6))) << 13) +
           ((size_t)(row & 63) << 7) +
           (size_t)((((col & 63) << 1)) ^ ((row & 7) << 4));
}

// ---------------------------------------------------------------------------
// zero the arrival counters (28 layers x 2 types x 8 bm, 128B-padded)
#define CNT_U32 14336
__global__ __launch_bounds__(256) void k_zero(uint32_t* c) {
    int i = blockIdx.x * 256 + threadIdx.x;
    if (i < CNT_U32) c[i] = 0;
}

// initial: h = hin; ximg = rmsnorm(hin, ln1[0]) image
__global__ __launch_bounds__(256) void k_start(
    const float* __restrict__ hin, float* __restrict__ h,
    const float* __restrict__ w, char* __restrict__ ximg)
{
    int t = blockIdx.x, tid = threadIdx.x;
    size_t base = (size_t)t * 1024 + tid * 4;
    float4 v = *(const float4*)(hin + base);
    *(float4*)(h + base) = v;
    float ss = v.x * v.x + v.y * v.y + v.z * v.z + v.w * v.w;
#pragma unroll
    for (int m = 1; m < 64; m <<= 1) ss += __shfl_xor(ss, m);
    __shared__ float red[4];
    if ((tid & 63) == 0) red[tid >> 6] = ss;
    __syncthreads();
    float tot = (red[0] + red[1]) + (red[2] + red[3]);
    float sc = rsqrtf(tot * (1.0f / 1024.0f) + 1e-6f);
    float4 wv4 = *(const float4*)(w + tid * 4);
    bf16x4 o;
    o[0] = (bf16_t)(v.x * sc * wv4.x);
    o[1] = (bf16_t)(v.y * sc * wv4.y);
    o[2] = (bf16_t)(v.z * sc * wv4.z);
    o[3] = (bf16_t)(v.w * sc * wv4.w);
    *(bf16x4*)(ximg + aoff(t, tid * 4, 16)) = o;
}

// ---------------------------------------------------------------------------
// weight tile convert: one 64x64 tile per block index b in [0,3840).
__device__ __forceinline__ void conv_tile(
    int b, int lay,
    const float* __restrict__ Wq, const float* __restrict__ Wk,
    const float* __restrict__ Wv, const float* __restrict__ Wo,
    const float* __restrict__ Wg, const float* __restrict__ Wu,
    const float* __restrict__ Wd, char* __restrict__ ib, void* smemv)
{
    const float* wq = Wq + (size_t)lay * 1024 * 2048;
    const float* wk = Wk + (size_t)lay * 1024 * 1024;
    const float* wv = Wv + (size_t)lay * 1024 * 1024;
    const float* wo = Wo + (size_t)lay * 2048 * 1024;
    const float* wg = Wg + (size_t)lay * 1024 * 3072;
    const float* wu = Wu + (size_t)lay * 1024 * 3072;
    const float* wd = Wd + (size_t)lay * 3072 * 1024;

    const float* src = nullptr;
    int ldbw = 0, n, kt, guMode = 0;
    size_t dstoff;
    if (b < 1024) {                      // qkv: 64 n x 16 kt
        n = b >> 4; kt = b & 15;
        int C0 = n * 64;
        if (C0 < 2048)      { src = wq + C0;          ldbw = 2048; }
        else if (C0 < 3072) { src = wk + (C0 - 2048); ldbw = 1024; }
        else                { src = wv + (C0 - 3072); ldbw = 1024; }
        src += (size_t)(kt * 64) * ldbw;
        dstoff = IMG_QKV + (size_t)b * 8192;
    } else if (b < 1536) {               // wo: 16 n x 32 kt
        int b2 = b - 1024; n = b2 >> 5; kt = b2 & 31;
        src = wo + (size_t)(kt * 64) * 1024 + n * 64; ldbw = 1024;
        dstoff = IMG_WO + (size_t)b2 * 8192;
    } else if (b < 3072) {               // gu: 96 n x 16 kt (g/u 16-interleave)
        int b3 = b - 1536; n = b3 >> 4; kt = b3 & 15;
        guMode = 1; ldbw = 3072;
        dstoff = IMG_GU + (size_t)b3 * 8192;
    } else {                             // wd: 16 n x 48 kt
        int b4 = b - 3072; n = b4 / 48; kt = b4 % 48;
        src = wd + (size_t)(kt * 64) * 1024 + n * 64; ldbw = 1024;
        dstoff = IMG_WD + (size_t)b4 * 8192;
    }

    float (*T)[68] = (float (*)[68])smemv;
    int tid = threadIdx.x;
    if (!guMode) {
#pragma unroll
        for (int it = 0; it < 4; ++it) {
            int idx = it * 256 + tid;
            int kk = idx >> 4, seg = idx & 15;
            *(float4*)&T[kk][seg * 4] = *(const float4*)(src + (size_t)kk * ldbw + seg * 4);
        }
    } else {
        const float* wg_ = wg + (size_t)(kt * 64) * 3072;
        const float* wu_ = wu + (size_t)(kt * 64) * 3072;
#pragma unroll
        for (int it = 0; it < 4; ++it) {
            int idx = it * 256 + tid;
            int kk = idx >> 4, seg = idx & 15;
            int nl = seg * 4;
            int colc = n * 32 + ((nl >> 5) & 1) * 16 + (nl & 15);
            const float* s2 = (((nl >> 4) & 1) ? wu_ : wg_) + (size_t)kk * 3072 + colc;
            *(float4*)&T[kk][nl] = *(const float4*)s2;
        }
    }
    __syncthreads();
    char* dst = ib + dstoff;
#pragma unroll
    for (int it = 0; it < 2; ++it) {
        int kg = tid & 7;
        int nrow = it * 32 + (tid >> 3);
        bf16x8 o;
#pragma unroll
        for (int j = 0; j < 8; ++j) o[j] = (bf16_t)T[kg * 8 + j][nrow];
        *(bf16x8*)(dst + nrow * 128 + ((kg * 16) ^ ((nrow & 7) << 4))) = o;
    }
}

__global__ __launch_bounds__(256) void k_conv(
    int lay,
    const float* __restrict__ Wq, const float* __restrict__ Wk,
    const float* __restrict__ Wv, const float* __restrict__ Wo,
    const float* __restrict__ Wg, const float* __restrict__ Wu,
    const float* __restrict__ Wd, char* __restrict__ img)
{
    __shared__ __align__(16) char smem[17408];
    conv_tile(blockIdx.x, lay, Wq, Wk, Wv, Wo, Wg, Wu, Wd, img, smem);
}

// ---------------------------------------------------------------------------
// GEMM main loop: BM=64, BN=128, BK=64; 4 waves (2x2), 32x64 per wave.
// 3-deep prefetch: stage(t+2); vmcnt(12); barrier; compute(t); barrier.
template <int NBN, int SPLITK, int LDAK>
__device__ __forceinline__ void gemm_loop(
    const char* __restrict__ Aimg, const char* __restrict__ Bimg,
    char* smem, int f, f32x4 (&acc)[2][4], int& bmO, int& bnO, int& sO)
{
    const int steps = LDAK / SPLITK;
    int bm = f / (NBN * SPLITK);
    int r = f % (NBN * SPLITK);
    int s = r / NBN;
    int bn = r % NBN;
    int k0d = s * steps;
    bmO = bm; bnO = bn; sO = s;

    int tid = threadIdx.x;
    int wv = tid >> 6, l = tid & 63, lg = l >> 4, lr = l & 15;
    int wr = wv >> 1, wc = wv & 1;

#pragma unroll
    for (int i = 0; i < 2; ++i)
#pragma unroll
        for (int j = 0; j < 4; ++j) { f32x4 z = {0.f, 0.f, 0.f, 0.f}; acc[i][j] = z; }

    auto stage = [&](int buf, int kt) {
        const char* ab = Aimg + ((size_t)(bm * LDAK + k0d + kt)) * 8192;
        const char* b0 = Bimg + ((size_t)((2 * bn) * LDAK + k0d + kt)) * 8192;
        const char* b1 = Bimg + ((size_t)((2 * bn + 1) * LDAK + k0d + kt)) * 8192;
        char* al = smem + buf * 24576;
        char* bl = al + 8192;
#pragma unroll
        for (int u = 0; u < 2; ++u) {
            int off = (wv * 2 + u) * 1024;
            gload16(ab + off + l * 16, al + off);
        }
#pragma unroll
        for (int u = 0; u < 4; ++u) {
            int off = (wv * 4 + u) * 1024;
            const char* src = (off < 8192) ? (b0 + off) : (b1 + off - 8192);
            gload16(src + l * 16, bl + off);
        }
    };
    auto compute = [&](int buf) {
        const char* as = smem + buf * 24576;
        const char* bs = as + 8192 + wc * 8192;
        __builtin_amdgcn_s_setprio(1);
#pragma unroll
        for (int c = 0; c < 2; ++c) {
            int co = (c * 64 + lg * 16) ^ ((lr & 7) << 4);
            bf16x8 af[2], bf[4];
#pragma unroll
            for (int i = 0; i < 2; ++i)
                af[i] = *(const bf16x8*)(as + (wr * 32 + i * 16 + lr) * 128 + co);
#pragma unroll
            for (int j = 0; j < 4; ++j)
                bf[j] = *(const bf16x8*)(bs + (j * 16 + lr) * 128 + co);
#pragma unroll
            for (int i = 0; i < 2; ++i)
#pragma unroll
                for (int j = 0; j < 4; ++j)
                    acc[i][j] = __builtin_amdgcn_mfma_f32_16x16x32_bf16(
                        af[i], bf[j], acc[i][j], 0, 0, 0);
        }
        __builtin_amdgcn_s_setprio(0);
    };

    stage(0, 0);
    stage(1, 1);
    int buf = 0;
    for (int kt = 0; kt < steps; ++kt) {
        if (kt + 2 < steps)      { stage((kt + 2) % 3, kt + 2); WAITV12; }
        else if (kt + 1 < steps) { WAITV6; }
        else                     { WAITV0; }
        __builtin_amdgcn_sched_barrier(0);
        __builtin_amdgcn_s_barrier();
        __builtin_amdgcn_sched_barrier(0);
        compute(buf);
        __builtin_amdgcn_s_barrier();
        buf = (buf == 2) ? 0 : buf + 1;
    }
}

// ---------------------------------------------------------------------------
// stream-K fixup: last-arriving block of a bm-group sums parts into h and
// writes the rms image (or the final f32 output).
// 4 threads per row: r=tid>>2, quarter=tid&3.
__device__ __forceinline__ void rms_fixup(
    int bm, float* __restrict__ h, const bf16_t* __restrict__ parts,
    const float* __restrict__ w, char* __restrict__ img,
    float* __restrict__ dout)
{
    int tid = threadIdx.x;
    int r = bm * 64 + (tid >> 2), q4 = tid & 3;
    float* hr = h + (size_t)r * 1024 + q4 * 256;
    const bf16_t* pr = parts + (size_t)r * 1024 + q4 * 256;
    float ss = 0.f;
    for (int c = 0; c < 64; ++c) {
        float4 v = *(const float4*)(hr + c * 4);
#pragma unroll
        for (int p = 0; p < 4; ++p) {
            bf16x4 a = *(const bf16x4*)(pr + (size_t)p * 524288 + c * 4);
            v.x += (float)a[0]; v.y += (float)a[1];
            v.z += (float)a[2]; v.w += (float)a[3];
        }
        if (dout) *(float4*)(dout + (size_t)r * 1024 + q4 * 256 + c * 4) = v;
        else      *(float4*)(hr + c * 4) = v;
        ss += v.x * v.x + v.y * v.y + v.z * v.z + v.w * v.w;
    }
    if (dout) return;
    ss += __shfl_xor(ss, 1);
    ss += __shfl_xor(ss, 2);
    float sc = rsqrtf(ss * (1.0f / 1024.0f) + 1e-6f);
    for (int c = 0; c < 64; ++c) {
        float4 v = *(const float4*)(hr + c * 4);
        int col = q4 * 256 + c * 4;
        bf16x4 o;
        o[0] = (bf16_t)(v.x * sc * w[col]);
        o[1] = (bf16_t)(v.y * sc * w[col + 1]);
        o[2] = (bf16_t)(v.z * sc * w[col + 2]);
        o[3] = (bf16_t)(v.w * sc * w[col + 3]);
        *(bf16x4*)(img + aoff(r, col, 16)) = o;
    }
}

// split-K GEMM + parts store + arrival; returns true if this block is last
// of its bm-group (32 blocks).
template <int LDAK>
__device__ __forceinline__ int part_job(
    int f, const char* A, const char* B, bf16_t* parts, char* smem,
    uint32_t* cnt, int& bmO)
{
    f32x4 acc[2][4];
    int bm, bn, s;
    gemm_loop<8, 4, LDAK>(A, B, smem, f, acc, bm, bn, s);
    bmO = bm;
    int tid = threadIdx.x;
    int wv = tid >> 6, l = tid & 63, lg = l >> 4, lr = l & 15;
    int wr = wv >> 1, wc = wv & 1;
    bf16_t* P = parts + (size_t)s * 524288;
#pragma unroll
    for (int i = 0; i < 2; ++i)
#pragma unroll
        for (int j = 0; j < 4; ++j)
#pragma unroll
            for (int ii = 0; ii < 4; ++ii) {
                int row = bm * 64 + wr * 32 + i * 16 + lg * 4 + ii;
                int col = bn * 128 + wc * 64 + j * 16 + lr;
                P[(size_t)row * 1024 + col] = (bf16_t)acc[i][j][ii];
            }
    // arrival
    __shared__ int lastf;
    __threadfence();
    if (tid == 0) {
        uint32_t old = __hip_atomic_fetch_add(cnt + bm * 32, 1u,
                                              __ATOMIC_ACQ_REL,
                                              __HIP_MEMORY_SCOPE_AGENT);
        lastf = (old == 31u);
    }
    __syncthreads();
    if (!lastf) return 0;
    __threadfence();
    return 1;
}

// ---------------------------------------------------------------------------
// qkv GEMM (image A) + fused q/k rmsnorm+rope / v-transpose epilogue,
// plus conv tiles [0,960).
__global__ __launch_bounds__(256) void g_qkvf(
    const char* __restrict__ Aimg, const char* __restrict__ Bimg,
    const float* __restrict__ cosb, const float* __restrict__ sinb,
    const float* __restrict__ qw, const float* __restrict__ kw,
    f16_t* __restrict__ qf, f16_t* __restrict__ kf, f16_t* __restrict__ vT,
    const float* Wq, const float* Wk, const float* Wv, const float* Wo,
    const float* Wg, const float* Wu, const float* Wd,
    int lnext, char* __restrict__ imgnext)
{
    __shared__ __align__(128) char smem[73728];
    if (blockIdx.x >= 256) {
        conv_tile(blockIdx.x - 256, lnext, Wq, Wk, Wv, Wo, Wg, Wu, Wd, imgnext, smem);
        return;
    }
    f32x4 acc[2][4];
    int bm, bn, s;
    gemm_loop<32, 1, 16>(Aimg, Bimg, smem, blockIdx.x, acc, bm, bn, s);

    int tid = threadIdx.x;
    int wv = tid >> 6, l = tid & 63, lg = l >> 4, lr = l & 15;
    int wr = wv >> 1, wc = wv & 1;
    float (*X)[132] = (float (*)[132])smem;
    __syncthreads();
#pragma unroll
    for (int i = 0; i < 2; ++i)
#pragma unroll
        for (int j = 0; j < 4; ++j)
#pragma unroll
            for (int ii = 0; ii < 4; ++ii)
                X[wr * 32 + i * 16 + lg * 4 + ii][wc * 64 + j * 16 + lr] = acc[i][j][ii];
    __syncthreads();

    int t0 = bm * 64;
    if (bn < 24) {
        bool isq = bn < 16;
        int slot = isq ? bn : bn - 16;
        const float* wn = isq ? qw : kw;
        int r = tid >> 2, part = tid & 3;
        float ss = 0.f;
#pragma unroll
        for (int c = 0; c < 32; ++c) { float v = X[r][part * 32 + c]; ss += v * v; }
        ss += __shfl_xor(ss, 1);
        ss += __shfl_xor(ss, 2);
        float sc = rsqrtf(ss * (1.0f / 128.0f) + 1e-6f);
        int t = t0 + r;
        int d0 = part * 16;
        float o1v[16], o2v[16];
#pragma unroll
        for (int c = 0; c < 16; ++c) {
            int d = d0 + c;
            float xv1 = X[r][d] * sc * wn[d];
            float xv2 = X[r][d + 64] * sc * wn[d + 64];
            o1v[c] = xv1 * cosb[t * HD + d] - xv2 * sinb[t * HD + d];
            o2v[c] = xv2 * cosb[t * HD + d + 64] + xv1 * sinb[t * HD + d + 64];
        }
        f16x8 w0, w1, w2, w3;
#pragma unroll
        for (int c = 0; c < 8; ++c) {
            w0[c] = (f16_t)o1v[c];     w1[c] = (f16_t)o1v[8 + c];
            w2[c] = (f16_t)o2v[c];     w3[c] = (f16_t)o2v[8 + c];
        }
        f16_t* o = (isq ? qf : kf) + ((size_t)slot * SEQ + t) * HD;
        *(f16x8*)(o + d0) = w0;
        *(f16x8*)(o + d0 + 8) = w1;
        *(f16x8*)(o + d0 + 64) = w2;
        *(f16x8*)(o + d0 + 72) = w3;
    } else {
        int kvh = bn - 24;
#pragma unroll
        for (int it = 0; it < 4; ++it) {
            int task = it * 256 + tid;
            int d = task >> 3, seg = task & 7;
            f16x8 o;
#pragma unroll
            for (int j = 0; j < 8; ++j) o[j] = (f16_t)X[seg * 8 + j][d];
            *(f16x8*)(vT + ((size_t)kvh * HD + d) * SEQ + t0 + seg * 8) = o;
        }
    }
}

// ---------------------------------------------------------------------------
// wo GEMM -> parts; last arriver per bm: h += parts, rms(ln2) -> yimg.
// conv tiles [960,1920).
__global__ __launch_bounds__(256) void g_wo(
    const char* A, const char* B, bf16_t* parts,
    float* __restrict__ h, char* __restrict__ yimg,
    const float* __restrict__ ln2v, uint32_t* __restrict__ cnt,
    const float* Wq, const float* Wk, const float* Wv, const float* Wo,
    const float* Wg, const float* Wu, const float* Wd,
    int lnext, char* imgnext)
{
    __shared__ __align__(128) char smem[73728];
    if (blockIdx.x >= 256) {
        conv_tile(blockIdx.x - 256 + 960, lnext, Wq, Wk, Wv, Wo, Wg, Wu, Wd, imgnext, smem);
        return;
    }
    int bm;
    if (part_job<32>(blockIdx.x, A, B, parts, smem, cnt, bm))
        rms_fixup(bm, h, parts, ln2v, yimg, nullptr);
}

// gu GEMM with fused swiglu -> mimg, plus conv tiles [1920,2880)
__global__ __launch_bounds__(256) void g_gu(
    const char* A, const char* B, char* mimg,
    const float* Wq, const float* Wk, const float* Wv, const float* Wo,
    const float* Wg, const float* Wu, const float* Wd,
    int lnext, char* imgnext)
{
    __shared__ __align__(128) char smem[73728];
    if (blockIdx.x >= 384) {
        conv_tile(blockIdx.x - 384 + 1920, lnext, Wq, Wk, Wv, Wo, Wg, Wu, Wd, imgnext, smem);
        return;
    }
    f32x4 acc[2][4];
    int bm, bn, s;
    gemm_loop<48, 1, 16>(A, B, smem, blockIdx.x, acc, bm, bn, s);
    int tid = threadIdx.x;
    int wv = tid >> 6, l = tid & 63, lg = l >> 4, lr = l & 15;
    int wr = wv >> 1, wc = wv & 1;
#pragma unroll
    for (int i = 0; i < 2; ++i)
#pragma unroll
        for (int jp = 0; jp < 2; ++jp)
#pragma unroll
            for (int ii = 0; ii < 4; ++ii) {
                int row = bm * 64 + wr * 32 + i * 16 + lg * 4 + ii;
                int col = (bn * 2 + wc) * 32 + jp * 16 + lr;
                float gv = acc[i][2 * jp][ii];
                float uv = acc[i][2 * jp + 1][ii];
                float val = gv / (1.f + __expf(-gv)) * uv;
                *(bf16_t*)(mimg + aoff(row, col, 48)) = (bf16_t)val;
            }
}

// wd GEMM -> parts; last arriver: h += parts, rms(ln1[l+1]) -> ximg,
// or (last layer) d_out = h + parts. conv tiles [2880,3840).
__global__ __launch_bounds__(256) void g_wd(
    const char* A, const char* B, bf16_t* parts,
    float* __restrict__ h, char* __restrict__ ximg,
    const float* __restrict__ ln1n, uint32_t* __restrict__ cnt,
    float* __restrict__ dout,
    const float* Wq, const float* Wk, const float* Wv, const float* Wo,
    const float* Wg, const float* Wu, const float* Wd,
    int lnext, char* imgnext)
{
    __shared__ __align__(128) char smem[73728];
    if (blockIdx.x >= 256) {
        conv_tile(blockIdx.x - 256 + 2880, lnext, Wq, Wk, Wv, Wo, Wg, Wu, Wd, imgnext, smem);
        return;
    }
    int bm;
    if (part_job<48>(blockIdx.x, A, B, parts, smem, cnt, bm))
        rms_fixup(bm, h, parts, ln1n, ximg, dout);
}

// ---------------------------------------------------------------------------
// causal flash attention -> attn-out image; heavy q-tiles launched first.
__global__ __launch_bounds__(128) void k_attn(
    const f16_t* __restrict__ qf, const f16_t* __restrict__ kf,
    const f16_t* __restrict__ vT, char* __restrict__ attimg)
{
    int h = blockIdx.x >> 4, qb = 15 - (blockIdx.x & 15);
    int kvh = h >> 1;
    __shared__ f16_t Kt[64][136];
    __shared__ f16_t Vt[128][72];
    __shared__ f16_t Pl[2][16][72];
    int tid = threadIdx.x;
    int wv = tid >> 6, l = tid & 63, lg = l >> 4, lr = l & 15;
    int q0 = qb * 32;
    int qrow = q0 + wv * 16;

    f16x8 aq[4];
    const f16_t* qp = qf + ((size_t)h * SEQ + qrow + lr) * HD;
#pragma unroll
    for (int c = 0; c < 4; ++c) aq[c] = *(const f16x8*)(qp + c * 32 + lg * 8);

    f32x4 accv[8];
#pragma unroll
    for (int df = 0; df < 8; ++df) { f32x4 z = {0.f, 0.f, 0.f, 0.f}; accv[df] = z; }
    float mrun[4], lrun[4];
#pragma unroll
    for (int ii = 0; ii < 4; ++ii) { mrun[ii] = -3e38f; lrun[ii] = 0.f; }

    int ktiles = (q0 + 32 + 63) >> 6;
    for (int kt = 0; kt < ktiles; ++kt) {
        int kt0 = kt * 64;
        __syncthreads();
#pragma unroll
        for (int it = 0; it < 8; ++it) {
            int idx = it * 128 + tid;
            int r = idx >> 4, seg = idx & 15;
            *(int4*)&Kt[r][seg * 8] =
                *(const int4*)(kf + ((size_t)kvh * SEQ + kt0 + r) * HD + seg * 8);
        }
#pragma unroll
        for (int it = 0; it < 8; ++it) {
            int idx = it * 128 + tid;
            int r = idx >> 3, seg = idx & 7;
            *(int4*)&Vt[r][seg * 8] =
                *(const int4*)(vT + ((size_t)kvh * HD + r) * SEQ + kt0 + seg * 8);
        }
        __syncthreads();

        f32x4 s[4];
#pragma unroll
        for (int nf = 0; nf < 4; ++nf) {
            f32x4 a = {0.f, 0.f, 0.f, 0.f};
#pragma unroll
            for (int c = 0; c < 4; ++c) {
                f16x8 bk = *(const f16x8*)&Kt[nf * 16 + lr][c * 32 + lg * 8];
                a = __builtin_amdgcn_mfma_f32_16x16x32_f16(aq[c], bk, a, 0, 0, 0);
            }
            s[nf] = a;
        }
        const float scale = 0.08838834764831845f;
        float tmax[4] = {-3e38f, -3e38f, -3e38f, -3e38f};
#pragma unroll
        for (int nf = 0; nf < 4; ++nf) {
            int ktg = kt0 + nf * 16 + lr;
#pragma unroll
            for (int ii = 0; ii < 4; ++ii) {
                int qg = qrow + lg * 4 + ii;
                float vv = s[nf][ii] * scale;
                vv = (ktg <= qg) ? vv : -1e30f;
                s[nf][ii] = vv;
                tmax[ii] = fmaxf(tmax[ii], vv);
            }
        }
#pragma unroll
        for (int m = 1; m < 16; m <<= 1)
#pragma unroll
            for (int ii = 0; ii < 4; ++ii)
                tmax[ii] = fmaxf(tmax[ii], __shfl_xor(tmax[ii], m));
        float corr[4];
#pragma unroll
        for (int ii = 0; ii < 4; ++ii) {
            float mnew = fmaxf(mrun[ii], tmax[ii]);
            corr[ii] = __expf(mrun[ii] - mnew);
            mrun[ii] = mnew;
        }
        float tsum[4] = {0.f, 0.f, 0.f, 0.f};
#pragma unroll
        for (int nf = 0; nf < 4; ++nf)
#pragma unroll
            for (int ii = 0; ii < 4; ++ii) {
                float pp = __expf(s[nf][ii] - mrun[ii]);
                s[nf][ii] = pp;
                tsum[ii] += pp;
            }
#pragma unroll
        for (int m = 1; m < 16; m <<= 1)
#pragma unroll
            for (int ii = 0; ii < 4; ++ii) tsum[ii] += __shfl_xor(tsum[ii], m);
#pragma unroll
        for (int ii = 0; ii < 4; ++ii) lrun[ii] = lrun[ii] * corr[ii] + tsum[ii];
#pragma unroll
        for (int df = 0; df < 8; ++df)
#pragma unroll
            for (int ii = 0; ii < 4; ++ii) accv[df][ii] *= corr[ii];
#pragma unroll
        for (int nf = 0; nf < 4; ++nf)
#pragma unroll
            for (int ii = 0; ii < 4; ++ii)
                Pl[wv][lg * 4 + ii][nf * 16 + lr] = (f16_t)s[nf][ii];
        __syncthreads();
#pragma unroll
        for (int c = 0; c < 2; ++c) {
            f16x8 ap = *(const f16x8*)&Pl[wv][lr][c * 32 + lg * 8];
#pragma unroll
            for (int df = 0; df < 8; ++df) {
                f16x8 bv = *(const f16x8*)&Vt[df * 16 + lr][c * 32 + lg * 8];
                accv[df] = __builtin_amdgcn_mfma_f32_16x16x32_f16(ap, bv, accv[df], 0, 0, 0);
            }
        }
    }
#pragma unroll
    for (int df = 0; df < 8; ++df)
#pragma unroll
        for (int ii = 0; ii < 4; ++ii) {
            int qg = qrow + lg * 4 + ii;
            int col = h * HD + df * 16 + lr;
            *(bf16_t*)(attimg + aoff(qg, col, 32)) =
                (bf16_t)(accv[df][ii] / lrun[ii]);
        }
}

// ---------------------------------------------------------------------------
extern "C" void kernel_launch(void* const* d_in, const int* in_sizes, int n_in,
                              void* d_out, int out_size, void* d_ws, size_t ws_size,
                              hipStream_t stream)
{
    const float* hin  = (const float*)d_in[0];
    const float* cosb = (const float*)d_in[1];
    const float* sinb = (const float*)d_in[2];
    const float* Wq = (const float*)d_in[4];
    const float* Wk = (const float*)d_in[5];
    const float* Wv = (const float*)d_in[6];
    const float* Wo = (const float*)d_in[7];
    const float* Wg = (const float*)d_in[8];
    const float* Wu = (const float*)d_in[9];
    const float* Wd = (const float*)d_in[10];
    const float* Ln1 = (const float*)d_in[11];
    const float* Ln2 = (const float*)d_in[12];
    const float* Qn = (const float*)d_in[13];
    const float* Kn = (const float*)d_in[14];

    char* p = (char*)d_ws;
    auto alloc = [&](size_t bytes) { char* r = p; p += bytes; return r; };
    float*  h     = (float*)alloc(2097152);
    bf16_t* parts = (bf16_t*)alloc(4194304);
    char*   ximg  = alloc(1048576);
    char*   yimg  = alloc(1048576);
    char*   attimg= alloc(2097152);
    char*   mimg  = alloc(3145728);
    f16_t*  qf    = (f16_t*)alloc(2097152);
    f16_t*  kf    = (f16_t*)alloc(1048576);
    f16_t*  vT    = (f16_t*)alloc(1048576);
    uint32_t* cnts= (uint32_t*)alloc(CNT_U32 * 4);     // 28 x 2 x 8, padded
    char*   imgA  = alloc(IMG_LAYER_BYTES);
    size_t fixed = (size_t)(imgA + IMG_LAYER_BYTES - (char*)d_ws);
    bool pp = ws_size >= fixed + IMG_LAYER_BYTES;
    char* imgB = pp ? alloc(IMG_LAYER_BYTES) : imgA;

    k_zero<<<(CNT_U32 + 255) / 256, 256, 0, stream>>>(cnts);
    k_start<<<512, 256, 0, stream>>>(hin, h, Ln1, ximg);
    k_conv<<<3840, 256, 0, stream>>>(0, Wq, Wk, Wv, Wo, Wg, Wu, Wd, imgA);

    for (int l = 0; l < 28; ++l) {
        char* img  = pp ? ((l & 1) ? imgB : imgA) : imgA;
        char* imgn = pp ? ((l & 1) ? imgA : imgB) : imgA;
        bool cv = pp && (l < 27);
        int ln = l + 1;
        uint32_t* cwo = cnts + (l * 2 + 0) * 256;
        uint32_t* cwd = cnts + (l * 2 + 1) * 256;

        if (!pp && l > 0)
            k_conv<<<3840, 256, 0, stream>>>(l, Wq, Wk, Wv, Wo, Wg, Wu, Wd, imgA);

        g_qkvf<<<cv ? 1216 : 256, 256, 0, stream>>>(
            ximg, img + IMG_QKV, cosb, sinb,
            Qn + (size_t)l * 128, Kn + (size_t)l * 128, qf, kf, vT,
            Wq, Wk, Wv, Wo, Wg, Wu, Wd, ln, imgn);
        k_attn<<<256, 128, 0, stream>>>(qf, kf, vT, attimg);
        g_wo<<<cv ? 1216 : 256, 256, 0, stream>>>(
            attimg, img + IMG_WO, parts, h, yimg,
            Ln2 + (size_t)l * 1024, cwo,
            Wq, Wk, Wv, Wo, Wg, Wu, Wd, ln, imgn);
        g_gu<<<cv ? 1344 : 384, 256, 0, stream>>>(
            yimg, img + IMG_GU, mimg,
            Wq, Wk, Wv, Wo, Wg, Wu, Wd, ln, imgn);
        g_wd<<<cv ? 1216 : 256, 256, 0, stream>>>(
            mimg, img + IMG_WD, parts, h, ximg,
            Ln1 + (size_t)ln * 1024, cwd,
            (l == 27) ? (float*)d_out : nullptr,
            Wq, Wk, Wv, Wo, Wg, Wu, Wd, ln, imgn);
    }
}

// Round 13
// 7386.550 us; speedup vs baseline: 2.4885x; 1.2097x over previous
//
#include <hip/hip_runtime.h>
#include <stdint.h>

// Qwen3 decoder, 28L, Q=512, D=1024, HQ=16, HKV=8, HD=128, DFF=3072.
// R13 = R12 stream-K last-arriver fixup, but FENCE-FREE visibility:
// parts written with agent-scope relaxed atomic stores (sc1, device-coherent,
// no L2 flush), local vmcnt(0) drain, RELAXED arrival counter (no wbl2),
// fixup reads parts with agent-scope relaxed loads. 5 kernels/layer.

typedef __bf16 bf16_t;
typedef _Float16 f16_t;
typedef __bf16 bf16x8 __attribute__((ext_vector_type(8)));
typedef __bf16 bf16x4 __attribute__((ext_vector_type(4)));
typedef _Float16 f16x8 __attribute__((ext_vector_type(8)));
typedef float f32x4 __attribute__((ext_vector_type(4)));

#define SEQ 512
#define HD 128

#define IMG_QKV 0ull
#define IMG_WO  8388608ull
#define IMG_GU  12582912ull
#define IMG_WD  25165824ull
#define IMG_LAYER_BYTES 31457280ull

typedef const __attribute__((address_space(1))) uint32_t as1_u32;
typedef __attribute__((address_space(3))) uint32_t as3_u32;

__device__ __forceinline__ void gload16(const void* g, void* l) {
    __builtin_amdgcn_global_load_lds((as1_u32*)g, (as3_u32*)l, 16, 0, 0);
}

#define WAITV12 asm volatile("s_waitcnt vmcnt(12)" ::: "memory")
#define WAITV6  asm volatile("s_waitcnt vmcnt(6)" ::: "memory")
#define WAITV0  asm volatile("s_waitcnt vmcnt(0)" ::: "memory")

__device__ __forceinline__ size_t aoff(int row, int col, int ldak) {
    return (((size_t)((row >> 6) * ldak + (col >> 6))) << 13) +
           ((size_t)(row & 63) << 7) +
           (size_t)((((col & 63) << 1)) ^ ((row & 7) << 4));
}

// ---------------------------------------------------------------------------
#define CNT_U32 14336
__global__ __launch_bounds__(256) void k_zero(uint32_t* c) {
    int i = blockIdx.x * 256 + threadIdx.x;
    if (i < CNT_U32) c[i] = 0;
}

// initial: h = hin; ximg = rmsnorm(hin, ln1[0]) image
__global__ __launch_bounds__(256) void k_start(
    const float* __restrict__ hin, float* __restrict__ h,
    const float* __restrict__ w, char* __restrict__ ximg)
{
    int t = blockIdx.x, tid = threadIdx.x;
    size_t base = (size_t)t * 1024 + tid * 4;
    float4 v = *(const float4*)(hin + base);
    *(float4*)(h + base) = v;
    float ss = v.x * v.x + v.y * v.y + v.z * v.z + v.w * v.w;
#pragma unroll
    for (int m = 1; m < 64; m <<= 1) ss += __shfl_xor(ss, m);
    __shared__ float red[4];
    if ((tid & 63) == 0) red[tid >> 6] = ss;
    __syncthreads();
    float tot = (red[0] + red[1]) + (red[2] + red[3]);
    float sc = rsqrtf(tot * (1.0f / 1024.0f) + 1e-6f);
    float4 wv4 = *(const float4*)(w + tid * 4);
    bf16x4 o;
    o[0] = (bf16_t)(v.x * sc * wv4.x);
    o[1] = (bf16_t)(v.y * sc * wv4.y);
    o[2] = (bf16_t)(v.z * sc * wv4.z);
    o[3] = (bf16_t)(v.w * sc * wv4.w);
    *(bf16x4*)(ximg + aoff(t, tid * 4, 16)) = o;
}

// ---------------------------------------------------------------------------
// weight tile convert: one 64x64 tile per block index b in [0,3840).
__device__ __forceinline__ void conv_tile(
    int b, int lay,
    const float* __restrict__ Wq, const float* __restrict__ Wk,
    const float* __restrict__ Wv, const float* __restrict__ Wo,
    const float* __restrict__ Wg, const float* __restrict__ Wu,
    const float* __restrict__ Wd, char* __restrict__ ib, void* smemv)
{
    const float* wq = Wq + (size_t)lay * 1024 * 2048;
    const float* wk = Wk + (size_t)lay * 1024 * 1024;
    const float* wv = Wv + (size_t)lay * 1024 * 1024;
    const float* wo = Wo + (size_t)lay * 2048 * 1024;
    const float* wg = Wg + (size_t)lay * 1024 * 3072;
    const float* wu = Wu + (size_t)lay * 1024 * 3072;
    const float* wd = Wd + (size_t)lay * 3072 * 1024;

    const float* src = nullptr;
    int ldbw = 0, n, kt, guMode = 0;
    size_t dstoff;
    if (b < 1024) {                      // qkv: 64 n x 16 kt
        n = b >> 4; kt = b & 15;
        int C0 = n * 64;
        if (C0 < 2048)      { src = wq + C0;          ldbw = 2048; }
        else if (C0 < 3072) { src = wk + (C0 - 2048); ldbw = 1024; }
        else                { src = wv + (C0 - 3072); ldbw = 1024; }
        src += (size_t)(kt * 64) * ldbw;
        dstoff = IMG_QKV + (size_t)b * 8192;
    } else if (b < 1536) {               // wo: 16 n x 32 kt
        int b2 = b - 1024; n = b2 >> 5; kt = b2 & 31;
        src = wo + (size_t)(kt * 64) * 1024 + n * 64; ldbw = 1024;
        dstoff = IMG_WO + (size_t)b2 * 8192;
    } else if (b < 3072) {               // gu: 96 n x 16 kt (g/u 16-interleave)
        int b3 = b - 1536; n = b3 >> 4; kt = b3 & 15;
        guMode = 1; ldbw = 3072;
        dstoff = IMG_GU + (size_t)b3 * 8192;
    } else {                             // wd: 16 n x 48 kt
        int b4 = b - 3072; n = b4 / 48; kt = b4 % 48;
        src = wd + (size_t)(kt * 64) * 1024 + n * 64; ldbw = 1024;
        dstoff = IMG_WD + (size_t)b4 * 8192;
    }

    float (*T)[68] = (float (*)[68])smemv;
    int tid = threadIdx.x;
    if (!guMode) {
#pragma unroll
        for (int it = 0; it < 4; ++it) {
            int idx = it * 256 + tid;
            int kk = idx >> 4, seg = idx & 15;
            *(float4*)&T[kk][seg * 4] = *(const float4*)(src + (size_t)kk * ldbw + seg * 4);
        }
    } else {
        const float* wg_ = wg + (size_t)(kt * 64) * 3072;
        const float* wu_ = wu + (size_t)(kt * 64) * 3072;
#pragma unroll
        for (int it = 0; it < 4; ++it) {
            int idx = it * 256 + tid;
            int kk = idx >> 4, seg = idx & 15;
            int nl = seg * 4;
            int colc = n * 32 + ((nl >> 5) & 1) * 16 + (nl & 15);
            const float* s2 = (((nl >> 4) & 1) ? wu_ : wg_) + (size_t)kk * 3072 + colc;
            *(float4*)&T[kk][nl] = *(const float4*)s2;
        }
    }
    __syncthreads();
    char* dst = ib + dstoff;
#pragma unroll
    for (int it = 0; it < 2; ++it) {
        int kg = tid & 7;
        int nrow = it * 32 + (tid >> 3);
        bf16x8 o;
#pragma unroll
        for (int j = 0; j < 8; ++j) o[j] = (bf16_t)T[kg * 8 + j][nrow];
        *(bf16x8*)(dst + nrow * 128 + ((kg * 16) ^ ((nrow & 7) << 4))) = o;
    }
}

__global__ __launch_bounds__(256) void k_conv(
    int lay,
    const float* __restrict__ Wq, const float* __restrict__ Wk,
    const float* __restrict__ Wv, const float* __restrict__ Wo,
    const float* __restrict__ Wg, const float* __restrict__ Wu,
    const float* __restrict__ Wd, char* __restrict__ img)
{
    __shared__ __align__(16) char smem[17408];
    conv_tile(blockIdx.x, lay, Wq, Wk, Wv, Wo, Wg, Wu, Wd, img, smem);
}

// ---------------------------------------------------------------------------
// GEMM main loop: BM=64, BN=128, BK=64; 4 waves (2x2), 32x64 per wave.
// 3-deep prefetch: stage(t+2); vmcnt(12); barrier; compute(t); barrier.
template <int NBN, int SPLITK, int LDAK>
__device__ __forceinline__ void gemm_loop(
    const char* __restrict__ Aimg, const char* __restrict__ Bimg,
    char* smem, int f, f32x4 (&acc)[2][4], int& bmO, int& bnO, int& sO)
{
    const int steps = LDAK / SPLITK;
    int bm = f / (NBN * SPLITK);
    int r = f % (NBN * SPLITK);
    int s = r / NBN;
    int bn = r % NBN;
    int k0d = s * steps;
    bmO = bm; bnO = bn; sO = s;

    int tid = threadIdx.x;
    int wv = tid >> 6, l = tid & 63, lg = l >> 4, lr = l & 15;
    int wr = wv >> 1, wc = wv & 1;

#pragma unroll
    for (int i = 0; i < 2; ++i)
#pragma unroll
        for (int j = 0; j < 4; ++j) { f32x4 z = {0.f, 0.f, 0.f, 0.f}; acc[i][j] = z; }

    auto stage = [&](int buf, int kt) {
        const char* ab = Aimg + ((size_t)(bm * LDAK + k0d + kt)) * 8192;
        const char* b0 = Bimg + ((size_t)((2 * bn) * LDAK + k0d + kt)) * 8192;
        const char* b1 = Bimg + ((size_t)((2 * bn + 1) * LDAK + k0d + kt)) * 8192;
        char* al = smem + buf * 24576;
        char* bl = al + 8192;
#pragma unroll
        for (int u = 0; u < 2; ++u) {
            int off = (wv * 2 + u) * 1024;
            gload16(ab + off + l * 16, al + off);
        }
#pragma unroll
        for (int u = 0; u < 4; ++u) {
            int off = (wv * 4 + u) * 1024;
            const char* src = (off < 8192) ? (b0 + off) : (b1 + off - 8192);
            gload16(src + l * 16, bl + off);
        }
    };
    auto compute = [&](int buf) {
        const char* as = smem + buf * 24576;
        const char* bs = as + 8192 + wc * 8192;
        __builtin_amdgcn_s_setprio(1);
#pragma unroll
        for (int c = 0; c < 2; ++c) {
            int co = (c * 64 + lg * 16) ^ ((lr & 7) << 4);
            bf16x8 af[2], bf[4];
#pragma unroll
            for (int i = 0; i < 2; ++i)
                af[i] = *(const bf16x8*)(as + (wr * 32 + i * 16 + lr) * 128 + co);
#pragma unroll
            for (int j = 0; j < 4; ++j)
                bf[j] = *(const bf16x8*)(bs + (j * 16 + lr) * 128 + co);
#pragma unroll
            for (int i = 0; i < 2; ++i)
#pragma unroll
                for (int j = 0; j < 4; ++j)
                    acc[i][j] = __builtin_amdgcn_mfma_f32_16x16x32_bf16(
                        af[i], bf[j], acc[i][j], 0, 0, 0);
        }
        __builtin_amdgcn_s_setprio(0);
    };

    stage(0, 0);
    stage(1, 1);
    int buf = 0;
    for (int kt = 0; kt < steps; ++kt) {
        if (kt + 2 < steps)      { stage((kt + 2) % 3, kt + 2); WAITV12; }
        else if (kt + 1 < steps) { WAITV6; }
        else                     { WAITV0; }
        __builtin_amdgcn_sched_barrier(0);
        __builtin_amdgcn_s_barrier();
        __builtin_amdgcn_sched_barrier(0);
        compute(buf);
        __builtin_amdgcn_s_barrier();
        buf = (buf == 2) ? 0 : buf + 1;
    }
}

// ---------------------------------------------------------------------------
// stream-K fixup: last arriver of a bm-group sums parts into h, writes the
// rms image (or d_out). parts read via agent-scope relaxed loads (sc1).
__device__ __forceinline__ void rms_fixup(
    int bm, float* __restrict__ h, const bf16_t* __restrict__ parts,
    const float* __restrict__ w, char* __restrict__ img,
    float* __restrict__ dout)
{
    int tid = threadIdx.x;
    int r = bm * 64 + (tid >> 2), q4 = tid & 3;
    float* hr = h + (size_t)r * 1024 + q4 * 256;
    const uint64_t* pr = (const uint64_t*)parts + (size_t)r * 256 + q4 * 64;
    float ss = 0.f;
    for (int c = 0; c < 64; ++c) {
        float4 v = *(const float4*)(hr + c * 4);
#pragma unroll
        for (int p = 0; p < 4; ++p) {
            uint64_t raw = __hip_atomic_load(pr + (size_t)p * 131072 + c,
                                             __ATOMIC_RELAXED,
                                             __HIP_MEMORY_SCOPE_AGENT);
            union { uint64_t u; bf16x4 b; } cv; cv.u = raw;
            v.x += (float)cv.b[0]; v.y += (float)cv.b[1];
            v.z += (float)cv.b[2]; v.w += (float)cv.b[3];
        }
        if (dout) *(float4*)(dout + (size_t)r * 1024 + q4 * 256 + c * 4) = v;
        else      *(float4*)(hr + c * 4) = v;
        ss += v.x * v.x + v.y * v.y + v.z * v.z + v.w * v.w;
    }
    if (dout) return;
    ss += __shfl_xor(ss, 1);
    ss += __shfl_xor(ss, 2);
    float sc = rsqrtf(ss * (1.0f / 1024.0f) + 1e-6f);
    for (int c = 0; c < 64; ++c) {
        float4 v = *(const float4*)(hr + c * 4);
        int col = q4 * 256 + c * 4;
        bf16x4 o;
        o[0] = (bf16_t)(v.x * sc * w[col]);
        o[1] = (bf16_t)(v.y * sc * w[col + 1]);
        o[2] = (bf16_t)(v.z * sc * w[col + 2]);
        o[3] = (bf16_t)(v.w * sc * w[col + 3]);
        *(bf16x4*)(img + aoff(r, col, 16)) = o;
    }
}

// split-K GEMM + sc1 parts store + relaxed arrival; true if last of bm-group.
template <int LDAK>
__device__ __forceinline__ int part_job(
    int f, const char* A, const char* B, bf16_t* parts, char* smem,
    uint32_t* cnt, int& bmO)
{
    f32x4 acc[2][4];
    int bm, bn, s;
    gemm_loop<8, 4, LDAK>(A, B, smem, f, acc, bm, bn, s);
    bmO = bm;
    int tid = threadIdx.x;
    int wv = tid >> 6, l = tid & 63, lg = l >> 4, lr = l & 15;
    int wr = wv >> 1, wc = wv & 1;
    uint16_t* P = (uint16_t*)parts + (size_t)s * 524288;
#pragma unroll
    for (int i = 0; i < 2; ++i)
#pragma unroll
        for (int j = 0; j < 4; ++j)
#pragma unroll
            for (int ii = 0; ii < 4; ++ii) {
                int row = bm * 64 + wr * 32 + i * 16 + lg * 4 + ii;
                int col = bn * 128 + wc * 64 + j * 16 + lr;
                union { bf16_t b; uint16_t u; } cv;
                cv.b = (bf16_t)acc[i][j][ii];
                __hip_atomic_store(&P[(size_t)row * 1024 + col], cv.u,
                                   __ATOMIC_RELAXED, __HIP_MEMORY_SCOPE_AGENT);
            }
    WAITV0;                               // drain sc1 stores to coherent point
    __syncthreads();
    __shared__ int lastf;
    if (tid == 0) {
        uint32_t old = __hip_atomic_fetch_add(cnt + bm * 32, 1u,
                                              __ATOMIC_RELAXED,
                                              __HIP_MEMORY_SCOPE_AGENT);
        lastf = (old == 31u);
    }
    __syncthreads();
    return lastf;
}

// ---------------------------------------------------------------------------
// qkv GEMM (image A) + fused q/k rmsnorm+rope / v-transpose epilogue,
// plus conv tiles [0,960).
__global__ __launch_bounds__(256) void g_qkvf(
    const char* __restrict__ Aimg, const char* __restrict__ Bimg,
    const float* __restrict__ cosb, const float* __restrict__ sinb,
    const float* __restrict__ qw, const float* __restrict__ kw,
    f16_t* __restrict__ qf, f16_t* __restrict__ kf, f16_t* __restrict__ vT,
    const float* Wq, const float* Wk, const float* Wv, const float* Wo,
    const float* Wg, const float* Wu, const float* Wd,
    int lnext, char* __restrict__ imgnext)
{
    __shared__ __align__(128) char smem[73728];
    if (blockIdx.x >= 256) {
        conv_tile(blockIdx.x - 256, lnext, Wq, Wk, Wv, Wo, Wg, Wu, Wd, imgnext, smem);
        return;
    }
    f32x4 acc[2][4];
    int bm, bn, s;
    gemm_loop<32, 1, 16>(Aimg, Bimg, smem, blockIdx.x, acc, bm, bn, s);

    int tid = threadIdx.x;
    int wv = tid >> 6, l = tid & 63, lg = l >> 4, lr = l & 15;
    int wr = wv >> 1, wc = wv & 1;
    float (*X)[132] = (float (*)[132])smem;
    __syncthreads();
#pragma unroll
    for (int i = 0; i < 2; ++i)
#pragma unroll
        for (int j = 0; j < 4; ++j)
#pragma unroll
            for (int ii = 0; ii < 4; ++ii)
                X[wr * 32 + i * 16 + lg * 4 + ii][wc * 64 + j * 16 + lr] = acc[i][j][ii];
    __syncthreads();

    int t0 = bm * 64;
    if (bn < 24) {
        bool isq = bn < 16;
        int slot = isq ? bn : bn - 16;
        const float* wn = isq ? qw : kw;
        int r = tid >> 2, part = tid & 3;
        float ss = 0.f;
#pragma unroll
        for (int c = 0; c < 32; ++c) { float v = X[r][part * 32 + c]; ss += v * v; }
        ss += __shfl_xor(ss, 1);
        ss += __shfl_xor(ss, 2);
        float sc = rsqrtf(ss * (1.0f / 128.0f) + 1e-6f);
        int t = t0 + r;
        int d0 = part * 16;
        float o1v[16], o2v[16];
#pragma unroll
        for (int c = 0; c < 16; ++c) {
            int d = d0 + c;
            float xv1 = X[r][d] * sc * wn[d];
            float xv2 = X[r][d + 64] * sc * wn[d + 64];
            o1v[c] = xv1 * cosb[t * HD + d] - xv2 * sinb[t * HD + d];
            o2v[c] = xv2 * cosb[t * HD + d + 64] + xv1 * sinb[t * HD + d + 64];
        }
        f16x8 w0, w1, w2, w3;
#pragma unroll
        for (int c = 0; c < 8; ++c) {
            w0[c] = (f16_t)o1v[c];     w1[c] = (f16_t)o1v[8 + c];
            w2[c] = (f16_t)o2v[c];     w3[c] = (f16_t)o2v[8 + c];
        }
        f16_t* o = (isq ? qf : kf) + ((size_t)slot * SEQ + t) * HD;
        *(f16x8*)(o + d0) = w0;
        *(f16x8*)(o + d0 + 8) = w1;
        *(f16x8*)(o + d0 + 64) = w2;
        *(f16x8*)(o + d0 + 72) = w3;
    } else {
        int kvh = bn - 24;
#pragma unroll
        for (int it = 0; it < 4; ++it) {
            int task = it * 256 + tid;
            int d = task >> 3, seg = task & 7;
            f16x8 o;
#pragma unroll
            for (int j = 0; j < 8; ++j) o[j] = (f16_t)X[seg * 8 + j][d];
            *(f16x8*)(vT + ((size_t)kvh * HD + d) * SEQ + t0 + seg * 8) = o;
        }
    }
}

// ---------------------------------------------------------------------------
// wo GEMM -> parts; last arriver: h += parts, rms(ln2) -> yimg.
// conv tiles [960,1920).
__global__ __launch_bounds__(256) void g_wo(
    const char* A, const char* B, bf16_t* parts,
    float* __restrict__ h, char* __restrict__ yimg,
    const float* __restrict__ ln2v, uint32_t* __restrict__ cnt,
    const float* Wq, const float* Wk, const float* Wv, const float* Wo,
    const float* Wg, const float* Wu, const float* Wd,
    int lnext, char* imgnext)
{
    __shared__ __align__(128) char smem[73728];
    if (blockIdx.x >= 256) {
        conv_tile(blockIdx.x - 256 + 960, lnext, Wq, Wk, Wv, Wo, Wg, Wu, Wd, imgnext, smem);
        return;
    }
    int bm;
    if (part_job<32>(blockIdx.x, A, B, parts, smem, cnt, bm))
        rms_fixup(bm, h, parts, ln2v, yimg, nullptr);
}

// gu GEMM with fused swiglu -> mimg, plus conv tiles [1920,2880)
__global__ __launch_bounds__(256) void g_gu(
    const char* A, const char* B, char* mimg,
    const float* Wq, const float* Wk, const float* Wv, const float* Wo,
    const float* Wg, const float* Wu, const float* Wd,
    int lnext, char* imgnext)
{
    __shared__ __align__(128) char smem[73728];
    if (blockIdx.x >= 384) {
        conv_tile(blockIdx.x - 384 + 1920, lnext, Wq, Wk, Wv, Wo, Wg, Wu, Wd, imgnext, smem);
        return;
    }
    f32x4 acc[2][4];
    int bm, bn, s;
    gemm_loop<48, 1, 16>(A, B, smem, blockIdx.x, acc, bm, bn, s);
    int tid = threadIdx.x;
    int wv = tid >> 6, l = tid & 63, lg = l >> 4, lr = l & 15;
    int wr = wv >> 1, wc = wv & 1;
#pragma unroll
    for (int i = 0; i < 2; ++i)
#pragma unroll
        for (int jp = 0; jp < 2; ++jp)
#pragma unroll
            for (int ii = 0; ii < 4; ++ii) {
                int row = bm * 64 + wr * 32 + i * 16 + lg * 4 + ii;
                int col = (bn * 2 + wc) * 32 + jp * 16 + lr;
                float gv = acc[i][2 * jp][ii];
                float uv = acc[i][2 * jp + 1][ii];
                float val = gv / (1.f + __expf(-gv)) * uv;
                *(bf16_t*)(mimg + aoff(row, col, 48)) = (bf16_t)val;
            }
}

// wd GEMM -> parts; last arriver: h += parts, rms(ln1[l+1]) -> ximg,
// or (last layer) d_out = h + parts. conv tiles [2880,3840).
__global__ __launch_bounds__(256) void g_wd(
    const char* A, const char* B, bf16_t* parts,
    float* __restrict__ h, char* __restrict__ ximg,
    const float* __restrict__ ln1n, uint32_t* __restrict__ cnt,
    float* __restrict__ dout,
    const float* Wq, const float* Wk, const float* Wv, const float* Wo,
    const float* Wg, const float* Wu, const float* Wd,
    int lnext, char* imgnext)
{
    __shared__ __align__(128) char smem[73728];
    if (blockIdx.x >= 256) {
        conv_tile(blockIdx.x - 256 + 2880, lnext, Wq, Wk, Wv, Wo, Wg, Wu, Wd, imgnext, smem);
        return;
    }
    int bm;
    if (part_job<48>(blockIdx.x, A, B, parts, smem, cnt, bm))
        rms_fixup(bm, h, parts, ln1n, ximg, dout);
}

// ---------------------------------------------------------------------------
// causal flash attention -> attn-out image; heavy q-tiles launched first.
__global__ __launch_bounds__(128) void k_attn(
    const f16_t* __restrict__ qf, const f16_t* __restrict__ kf,
    const f16_t* __restrict__ vT, char* __restrict__ attimg)
{
    int h = blockIdx.x >> 4, qb = 15 - (blockIdx.x & 15);
    int kvh = h >> 1;
    __shared__ f16_t Kt[64][136];
    __shared__ f16_t Vt[128][72];
    __shared__ f16_t Pl[2][16][72];
    int tid = threadIdx.x;
    int wv = tid >> 6, l = tid & 63, lg = l >> 4, lr = l & 15;
    int q0 = qb * 32;
    int qrow = q0 + wv * 16;

    f16x8 aq[4];
    const f16_t* qp = qf + ((size_t)h * SEQ + qrow + lr) * HD;
#pragma unroll
    for (int c = 0; c < 4; ++c) aq[c] = *(const f16x8*)(qp + c * 32 + lg * 8);

    f32x4 accv[8];
#pragma unroll
    for (int df = 0; df < 8; ++df) { f32x4 z = {0.f, 0.f, 0.f, 0.f}; accv[df] = z; }
    float mrun[4], lrun[4];
#pragma unroll
    for (int ii = 0; ii < 4; ++ii) { mrun[ii] = -3e38f; lrun[ii] = 0.f; }

    int ktiles = (q0 + 32 + 63) >> 6;
    for (int kt = 0; kt < ktiles; ++kt) {
        int kt0 = kt * 64;
        __syncthreads();
#pragma unroll
        for (int it = 0; it < 8; ++it) {
            int idx = it * 128 + tid;
            int r = idx >> 4, seg = idx & 15;
            *(int4*)&Kt[r][seg * 8] =
                *(const int4*)(kf + ((size_t)kvh * SEQ + kt0 + r) * HD + seg * 8);
        }
#pragma unroll
        for (int it = 0; it < 8; ++it) {
            int idx = it * 128 + tid;
            int r = idx >> 3, seg = idx & 7;
            *(int4*)&Vt[r][seg * 8] =
                *(const int4*)(vT + ((size_t)kvh * HD + r) * SEQ + kt0 + seg * 8);
        }
        __syncthreads();

        f32x4 s[4];
#pragma unroll
        for (int nf = 0; nf < 4; ++nf) {
            f32x4 a = {0.f, 0.f, 0.f, 0.f};
#pragma unroll
            for (int c = 0; c < 4; ++c) {
                f16x8 bk = *(const f16x8*)&Kt[nf * 16 + lr][c * 32 + lg * 8];
                a = __builtin_amdgcn_mfma_f32_16x16x32_f16(aq[c], bk, a, 0, 0, 0);
            }
            s[nf] = a;
        }
        const float scale = 0.08838834764831845f;
        float tmax[4] = {-3e38f, -3e38f, -3e38f, -3e38f};
#pragma unroll
        for (int nf = 0; nf < 4; ++nf) {
            int ktg = kt0 + nf * 16 + lr;
#pragma unroll
            for (int ii = 0; ii < 4; ++ii) {
                int qg = qrow + lg * 4 + ii;
                float vv = s[nf][ii] * scale;
                vv = (ktg <= qg) ? vv : -1e30f;
                s[nf][ii] = vv;
                tmax[ii] = fmaxf(tmax[ii], vv);
            }
        }
#pragma unroll
        for (int m = 1; m < 16; m <<= 1)
#pragma unroll
            for (int ii = 0; ii < 4; ++ii)
                tmax[ii] = fmaxf(tmax[ii], __shfl_xor(tmax[ii], m));
        float corr[4];
#pragma unroll
        for (int ii = 0; ii < 4; ++ii) {
            float mnew = fmaxf(mrun[ii], tmax[ii]);
            corr[ii] = __expf(mrun[ii] - mnew);
            mrun[ii] = mnew;
        }
        float tsum[4] = {0.f, 0.f, 0.f, 0.f};
#pragma unroll
        for (int nf = 0; nf < 4; ++nf)
#pragma unroll
            for (int ii = 0; ii < 4; ++ii) {
                float pp = __expf(s[nf][ii] - mrun[ii]);
                s[nf][ii] = pp;
                tsum[ii] += pp;
            }
#pragma unroll
        for (int m = 1; m < 16; m <<= 1)
#pragma unroll
            for (int ii = 0; ii < 4; ++ii) tsum[ii] += __shfl_xor(tsum[ii], m);
#pragma unroll
        for (int ii = 0; ii < 4; ++ii) lrun[ii] = lrun[ii] * corr[ii] + tsum[ii];
#pragma unroll
        for (int df = 0; df < 8; ++df)
#pragma unroll
            for (int ii = 0; ii < 4; ++ii) accv[df][ii] *= corr[ii];
#pragma unroll
        for (int nf = 0; nf < 4; ++nf)
#pragma unroll
            for (int ii = 0; ii < 4; ++ii)
                Pl[wv][lg * 4 + ii][nf * 16 + lr] = (f16_t)s[nf][ii];
        __syncthreads();
#pragma unroll
        for (int c = 0; c < 2; ++c) {
            f16x8 ap = *(const f16x8*)&Pl[wv][lr][c * 32 + lg * 8];
#pragma unroll
            for (int df = 0; df < 8; ++df) {
                f16x8 bv = *(const f16x8*)&Vt[df * 16 + lr][c * 32 + lg * 8];
                accv[df] = __builtin_amdgcn_mfma_f32_16x16x32_f16(ap, bv, accv[df], 0, 0, 0);
            }
        }
    }
#pragma unroll
    for (int df = 0; df < 8; ++df)
#pragma unroll
        for (int ii = 0; ii < 4; ++ii) {
            int qg = qrow + lg * 4 + ii;
            int col = h * HD + df * 16 + lr;
            *(bf16_t*)(attimg + aoff(qg, col, 32)) =
                (bf16_t)(accv[df][ii] / lrun[ii]);
        }
}

// ---------------------------------------------------------------------------
extern "C" void kernel_launch(void* const* d_in, const int* in_sizes, int n_in,
                              void* d_out, int out_size, void* d_ws, size_t ws_size,
                              hipStream_t stream)
{
    const float* hin  = (const float*)d_in[0];
    const float* cosb = (const float*)d_in[1];
    const float* sinb = (const float*)d_in[2];
    const float* Wq = (const float*)d_in[4];
    const float* Wk = (const float*)d_in[5];
    const float* Wv = (const float*)d_in[6];
    const float* Wo = (const float*)d_in[7];
    const float* Wg = (const float*)d_in[8];
    const float* Wu = (const float*)d_in[9];
    const float* Wd = (const float*)d_in[10];
    const float* Ln1 = (const float*)d_in[11];
    const float* Ln2 = (const float*)d_in[12];
    const float* Qn = (const float*)d_in[13];
    const float* Kn = (const float*)d_in[14];

    char* p = (char*)d_ws;
    auto alloc = [&](size_t bytes) { char* r = p; p += bytes; return r; };
    float*  h     = (float*)alloc(2097152);
    bf16_t* parts = (bf16_t*)alloc(4194304);
    char*   ximg  = alloc(1048576);
    char*   yimg  = alloc(1048576);
    char*   attimg= alloc(2097152);
    char*   mimg  = alloc(3145728);
    f16_t*  qf    = (f16_t*)alloc(2097152);
    f16_t*  kf    = (f16_t*)alloc(1048576);
    f16_t*  vT    = (f16_t*)alloc(1048576);
    uint32_t* cnts= (uint32_t*)alloc(CNT_U32 * 4);
    char*   imgA  = alloc(IMG_LAYER_BYTES);
    size_t fixed = (size_t)(imgA + IMG_LAYER_BYTES - (char*)d_ws);
    bool pp = ws_size >= fixed + IMG_LAYER_BYTES;
    char* imgB = pp ? alloc(IMG_LAYER_BYTES) : imgA;

    k_zero<<<(CNT_U32 + 255) / 256, 256, 0, stream>>>(cnts);
    k_start<<<512, 256, 0, stream>>>(hin, h, Ln1, ximg);
    k_conv<<<3840, 256, 0, stream>>>(0, Wq, Wk, Wv, Wo, Wg, Wu, Wd, imgA);

    for (int l = 0; l < 28; ++l) {
        char* img  = pp ? ((l & 1) ? imgB : imgA) : imgA;
        char* imgn = pp ? ((l & 1) ? imgA : imgB) : imgA;
        bool cv = pp && (l < 27);
        int ln = l + 1;
        uint32_t* cwo = cnts + (l * 2 + 0) * 256;
        uint32_t* cwd = cnts + (l * 2 + 1) * 256;

        if (!pp && l > 0)
            k_conv<<<3840, 256, 0, stream>>>(l, Wq, Wk, Wv, Wo, Wg, Wu, Wd, imgA);

        g_qkvf<<<cv ? 1216 : 256, 256, 0, stream>>>(
            ximg, img + IMG_QKV, cosb, sinb,
            Qn + (size_t)l * 128, Kn + (size_t)l * 128, qf, kf, vT,
            Wq, Wk, Wv, Wo, Wg, Wu, Wd, ln, imgn);
        k_attn<<<256, 128, 0, stream>>>(qf, kf, vT, attimg);
        g_wo<<<cv ? 1216 : 256, 256, 0, stream>>>(
            attimg, img + IMG_WO, parts, h, yimg,
            Ln2 + (size_t)l * 1024, cwo,
            Wq, Wk, Wv, Wo, Wg, Wu, Wd, ln, imgn);
        g_gu<<<cv ? 1344 : 384, 256, 0, stream>>>(
            yimg, img + IMG_GU, mimg,
            Wq, Wk, Wv, Wo, Wg, Wu, Wd, ln, imgn);
        g_wd<<<cv ? 1216 : 256, 256, 0, stream>>>(
            mimg, img + IMG_WD, parts, h, ximg,
            Ln1 + (size_t)ln * 1024, cwd,
            (l == 27) ? (float*)d_out : nullptr,
            Wq, Wk, Wv, Wo, Wg, Wu, Wd, ln, imgn);
    }
}

// Round 14
// 2329.762 us; speedup vs baseline: 7.8899x; 3.1705x over previous
//
#include <hip/hip_runtime.h>
#include <stdint.h>

// Qwen3 decoder, 28L, Q=512, D=1024, HQ=16, HKV=8, HD=128, DFF=3072.
// R14 = revert to R6 (best measured: 2331 us). Next-layer weight conv
// distributed across all 4 GEMM kernels (overlaps HBM weight stream with
// MFMA); attention heavy-tiles-first; counted-vmcnt 2-barrier GEMM K-loop;
// fused qkv epilogue (qknorm+rope+vT); split-K4 bf16 partials folded into
// the two k_rms kernels.
//
// Post-R6 experiments (all reverted): 3-deep prefetch (R8: neutral),
// persistent mega-kernel w/ grid barriers (R7/R11: 8-18x regression,
// cross-XCD sync), rms-into-GEMM fusion via split-K1 (R9: +1.3ms),
// f32 atomicAdd residual (R10: +0.8ms), stream-K last-arriver fixup with
// fences (R12: +6.6ms) or sc1 coherent stores (R13: +5ms). The per-layer
// kernel-boundary cost (~50us/layer) is a structural floor of the 8-XCD
// non-coherent-L2 architecture for this dependency chain.

typedef __bf16 bf16_t;
typedef _Float16 f16_t;
typedef __bf16 bf16x8 __attribute__((ext_vector_type(8)));
typedef __bf16 bf16x4 __attribute__((ext_vector_type(4)));
typedef _Float16 f16x8 __attribute__((ext_vector_type(8)));
typedef float f32x4 __attribute__((ext_vector_type(4)));

#define SEQ 512
#define NHQ 16
#define NHKV 8
#define HD 128

#define IMG_QKV 0ull
#define IMG_WO  8388608ull
#define IMG_GU  12582912ull
#define IMG_WD  25165824ull
#define IMG_LAYER_BYTES 31457280ull

typedef const __attribute__((address_space(1))) uint32_t as1_u32;
typedef __attribute__((address_space(3))) uint32_t as3_u32;

__device__ __forceinline__ void gload16(const void* g, void* l) {
    __builtin_amdgcn_global_load_lds((as1_u32*)g, (as3_u32*)l, 16, 0, 0);
}

#define WAITV6 asm volatile("s_waitcnt vmcnt(6)" ::: "memory")
#define WAITV0 asm volatile("s_waitcnt vmcnt(0)" ::: "memory")

// byte offset into tiled-swizzled image (64x64 bf16 tiles, 8KB, [rowblk][kt])
__device__ __forceinline__ size_t aoff(int row, int col, int ldak) {
    return (((size_t)((row >> 6) * ldak + (col >> 6))) << 13) +
           ((size_t)(row & 63) << 7) +
           (size_t)((((col & 63) << 1)) ^ ((row & 7) << 4));
}

// ---------------------------------------------------------------------------
__global__ __launch_bounds__(256) void k_copy(const float* __restrict__ src,
                                              float* __restrict__ dst)
{
    size_t i = ((size_t)blockIdx.x * 256 + threadIdx.x) * 4;
    *(float4*)(dst + i) = *(const float4*)(src + i);
}

// ---------------------------------------------------------------------------
// weight tile convert: one 64x64 tile per block index b in [0,3840).
__device__ __forceinline__ void conv_tile(
    int b, int lay,
    const float* __restrict__ Wq, const float* __restrict__ Wk,
    const float* __restrict__ Wv, const float* __restrict__ Wo,
    const float* __restrict__ Wg, const float* __restrict__ Wu,
    const float* __restrict__ Wd, char* __restrict__ ib, void* smemv)
{
    const float* wq = Wq + (size_t)lay * 1024 * 2048;
    const float* wk = Wk + (size_t)lay * 1024 * 1024;
    const float* wv = Wv + (size_t)lay * 1024 * 1024;
    const float* wo = Wo + (size_t)lay * 2048 * 1024;
    const float* wg = Wg + (size_t)lay * 1024 * 3072;
    const float* wu = Wu + (size_t)lay * 1024 * 3072;
    const float* wd = Wd + (size_t)lay * 3072 * 1024;

    const float* src = nullptr;
    int ldbw = 0, n, kt, guMode = 0;
    size_t dstoff;
    if (b < 1024) {                      // qkv: 64 n x 16 kt
        n = b >> 4; kt = b & 15;
        int C0 = n * 64;
        if (C0 < 2048)      { src = wq + C0;          ldbw = 2048; }
        else if (C0 < 3072) { src = wk + (C0 - 2048); ldbw = 1024; }
        else                { src = wv + (C0 - 3072); ldbw = 1024; }
        src += (size_t)(kt * 64) * ldbw;
        dstoff = IMG_QKV + (size_t)b * 8192;
    } else if (b < 1536) {               // wo: 16 n x 32 kt
        int b2 = b - 1024; n = b2 >> 5; kt = b2 & 31;
        src = wo + (size_t)(kt * 64) * 1024 + n * 64; ldbw = 1024;
        dstoff = IMG_WO + (size_t)b2 * 8192;
    } else if (b < 3072) {               // gu: 96 n x 16 kt (g/u 16-interleave)
        int b3 = b - 1536; n = b3 >> 4; kt = b3 & 15;
        guMode = 1; ldbw = 3072;
        dstoff = IMG_GU + (size_t)b3 * 8192;
    } else {                             // wd: 16 n x 48 kt
        int b4 = b - 3072; n = b4 / 48; kt = b4 % 48;
        src = wd + (size_t)(kt * 64) * 1024 + n * 64; ldbw = 1024;
        dstoff = IMG_WD + (size_t)b4 * 8192;
    }

    float (*T)[68] = (float (*)[68])smemv;
    int tid = threadIdx.x;
    if (!guMode) {
#pragma unroll
        for (int it = 0; it < 4; ++it) {
            int idx = it * 256 + tid;
            int kk = idx >> 4, seg = idx & 15;
            *(float4*)&T[kk][seg * 4] = *(const float4*)(src + (size_t)kk * ldbw + seg * 4);
        }
    } else {
        const float* wg_ = wg + (size_t)(kt * 64) * 3072;
        const float* wu_ = wu + (size_t)(kt * 64) * 3072;
#pragma unroll
        for (int it = 0; it < 4; ++it) {
            int idx = it * 256 + tid;
            int kk = idx >> 4, seg = idx & 15;
            int nl = seg * 4;
            int colc = n * 32 + ((nl >> 5) & 1) * 16 + (nl & 15);
            const float* s2 = (((nl >> 4) & 1) ? wu_ : wg_) + (size_t)kk * 3072 + colc;
            *(float4*)&T[kk][nl] = *(const float4*)s2;
        }
    }
    __syncthreads();
    char* dst = ib + dstoff;
#pragma unroll
    for (int it = 0; it < 2; ++it) {
        int kg = tid & 7;
        int nrow = it * 32 + (tid >> 3);
        bf16x8 o;
#pragma unroll
        for (int j = 0; j < 8; ++j) o[j] = (bf16_t)T[kg * 8 + j][nrow];
        *(bf16x8*)(dst + nrow * 128 + ((kg * 16) ^ ((nrow & 7) << 4))) = o;
    }
}

__global__ __launch_bounds__(256) void k_conv(
    int lay,
    const float* __restrict__ Wq, const float* __restrict__ Wk,
    const float* __restrict__ Wv, const float* __restrict__ Wo,
    const float* __restrict__ Wg, const float* __restrict__ Wu,
    const float* __restrict__ Wd, char* __restrict__ img)
{
    __shared__ __align__(16) char smem[17408];
    conv_tile(blockIdx.x, lay, Wq, Wk, Wv, Wo, Wg, Wu, Wd, img, smem);
}

// ---------------------------------------------------------------------------
// residual(+4 bf16 splitK partials) + RMSNorm -> bf16 tiled-swizzled image
__global__ __launch_bounds__(256) void k_rms(
    float* __restrict__ h, const bf16_t* __restrict__ parts, int nparts,
    const float* __restrict__ w, char* __restrict__ ximg)
{
    int t = blockIdx.x, tid = threadIdx.x;
    size_t base = (size_t)t * 1024 + tid * 4;
    float4 v = *(const float4*)(h + base);
    for (int p = 0; p < nparts; ++p) {
        bf16x4 a = *(const bf16x4*)(parts + (size_t)p * 524288 + base);
        v.x += (float)a[0]; v.y += (float)a[1]; v.z += (float)a[2]; v.w += (float)a[3];
    }
    if (nparts) *(float4*)(h + base) = v;
    float ss = v.x * v.x + v.y * v.y + v.z * v.z + v.w * v.w;
#pragma unroll
    for (int m = 1; m < 64; m <<= 1) ss += __shfl_xor(ss, m);
    __shared__ float red[4];
    if ((tid & 63) == 0) red[tid >> 6] = ss;
    __syncthreads();
    float tot = (red[0] + red[1]) + (red[2] + red[3]);
    float sc = rsqrtf(tot * (1.0f / 1024.0f) + 1e-6f);
    float4 wv4 = *(const float4*)(w + tid * 4);
    bf16x4 o;
    o[0] = (bf16_t)(v.x * sc * wv4.x);
    o[1] = (bf16_t)(v.y * sc * wv4.y);
    o[2] = (bf16_t)(v.z * sc * wv4.z);
    o[3] = (bf16_t)(v.w * sc * wv4.w);
    *(bf16x4*)(ximg + aoff(t, tid * 4, 16)) = o;
}

// ---------------------------------------------------------------------------
__global__ __launch_bounds__(256) void k_finalize(
    const float* __restrict__ h, const bf16_t* __restrict__ parts,
    float* __restrict__ out)
{
    size_t base = ((size_t)blockIdx.x * 256 + threadIdx.x) * 4;
    float4 v = *(const float4*)(h + base);
#pragma unroll
    for (int p = 0; p < 4; ++p) {
        bf16x4 a = *(const bf16x4*)(parts + (size_t)p * 524288 + base);
        v.x += (float)a[0]; v.y += (float)a[1]; v.z += (float)a[2]; v.w += (float)a[3];
    }
    *(float4*)(out + base) = v;
}

// ---------------------------------------------------------------------------
// GEMM main loop: BM=64, BN=128, BK=64; 4 waves (2x2), 32x64 per wave.
// Counted-vmcnt pipeline: stage(t+1); vmcnt(6); barrier; compute(t); barrier.
template <int NBN, int SPLITK, int LDAK>
__device__ __forceinline__ void gemm_loop(
    const char* __restrict__ Aimg, const char* __restrict__ Bimg,
    char* smem, int f, f32x4 (&acc)[2][4], int& bmO, int& bnO, int& sO)
{
    const int steps = LDAK / SPLITK;
    int bm = f / (NBN * SPLITK);
    int r = f % (NBN * SPLITK);
    int s = r / NBN;
    int bn = r % NBN;
    int k0d = s * steps;
    bmO = bm; bnO = bn; sO = s;

    int tid = threadIdx.x;
    int wv = tid >> 6, l = tid & 63, lg = l >> 4, lr = l & 15;
    int wr = wv >> 1, wc = wv & 1;

#pragma unroll
    for (int i = 0; i < 2; ++i)
#pragma unroll
        for (int j = 0; j < 4; ++j) { f32x4 z = {0.f, 0.f, 0.f, 0.f}; acc[i][j] = z; }

    auto stage = [&](int buf, int kt) {
        const char* ab = Aimg + ((size_t)(bm * LDAK + k0d + kt)) * 8192;
        const char* b0 = Bimg + ((size_t)((2 * bn) * LDAK + k0d + kt)) * 8192;
        const char* b1 = Bimg + ((size_t)((2 * bn + 1) * LDAK + k0d + kt)) * 8192;
        char* al = smem + buf * 24576;
        char* bl = al + 8192;
#pragma unroll
        for (int u = 0; u < 2; ++u) {
            int off = (wv * 2 + u) * 1024;
            gload16(ab + off + l * 16, al + off);
        }
#pragma unroll
        for (int u = 0; u < 4; ++u) {
            int off = (wv * 4 + u) * 1024;
            const char* src = (off < 8192) ? (b0 + off) : (b1 + off - 8192);
            gload16(src + l * 16, bl + off);
        }
    };
    auto compute = [&](int buf) {
        const char* as = smem + buf * 24576;
        const char* bs = as + 8192 + wc * 8192;
        __builtin_amdgcn_s_setprio(1);
#pragma unroll
        for (int c = 0; c < 2; ++c) {
            int co = (c * 64 + lg * 16) ^ ((lr & 7) << 4);
            bf16x8 af[2], bf[4];
#pragma unroll
            for (int i = 0; i < 2; ++i)
                af[i] = *(const bf16x8*)(as + (wr * 32 + i * 16 + lr) * 128 + co);
#pragma unroll
            for (int j = 0; j < 4; ++j)
                bf[j] = *(const bf16x8*)(bs + (j * 16 + lr) * 128 + co);
#pragma unroll
            for (int i = 0; i < 2; ++i)
#pragma unroll
                for (int j = 0; j < 4; ++j)
                    acc[i][j] = __builtin_amdgcn_mfma_f32_16x16x32_bf16(
                        af[i], bf[j], acc[i][j], 0, 0, 0);
        }
        __builtin_amdgcn_s_setprio(0);
    };

    stage(0, 0);
    int buf = 0;
    for (int kt = 0; kt < steps; ++kt) {
        if (kt + 1 < steps) { stage(buf ^ 1, kt + 1); WAITV6; }
        else                { WAITV0; }
        __builtin_amdgcn_sched_barrier(0);
        __builtin_amdgcn_s_barrier();
        __builtin_amdgcn_sched_barrier(0);
        compute(buf);
        __builtin_amdgcn_s_barrier();
        buf ^= 1;
    }
}

// ---------------------------------------------------------------------------
// qkv GEMM with fused q/k rmsnorm+rope and v transpose (BN=128 = one head),
// plus distributed next-layer conv blocks.
__global__ __launch_bounds__(256) void g_qkvf(
    const char* __restrict__ Aimg, const char* __restrict__ Bimg,
    const float* __restrict__ cosb, const float* __restrict__ sinb,
    const float* __restrict__ qw, const float* __restrict__ kw,
    f16_t* __restrict__ qf, f16_t* __restrict__ kf, f16_t* __restrict__ vT,
    const float* Wq, const float* Wk, const float* Wv, const float* Wo,
    const float* Wg, const float* Wu, const float* Wd,
    int lnext, char* __restrict__ imgnext)
{
    __shared__ __align__(128) char smem[49152];
    if (blockIdx.x >= 256) {
        conv_tile(blockIdx.x - 256, lnext, Wq, Wk, Wv, Wo, Wg, Wu, Wd, imgnext, smem);
        return;
    }
    f32x4 acc[2][4];
    int bm, bn, s;
    gemm_loop<32, 1, 16>(Aimg, Bimg, smem, blockIdx.x, acc, bm, bn, s);

    int tid = threadIdx.x;
    int wv = tid >> 6, l = tid & 63, lg = l >> 4, lr = l & 15;
    int wr = wv >> 1, wc = wv & 1;
    float (*X)[132] = (float (*)[132])smem;
#pragma unroll
    for (int i = 0; i < 2; ++i)
#pragma unroll
        for (int j = 0; j < 4; ++j)
#pragma unroll
            for (int ii = 0; ii < 4; ++ii)
                X[wr * 32 + i * 16 + lg * 4 + ii][wc * 64 + j * 16 + lr] = acc[i][j][ii];
    __syncthreads();

    int t0 = bm * 64;
    if (bn < 24) {
        bool isq = bn < 16;
        int slot = isq ? bn : bn - 16;
        const float* wn = isq ? qw : kw;
        int r = tid >> 2, part = tid & 3;
        float ss = 0.f;
#pragma unroll
        for (int c = 0; c < 32; ++c) { float v = X[r][part * 32 + c]; ss += v * v; }
        ss += __shfl_xor(ss, 1);
        ss += __shfl_xor(ss, 2);
        float sc = rsqrtf(ss * (1.0f / 128.0f) + 1e-6f);
        int t = t0 + r;
        int d0 = part * 16;
        float o1v[16], o2v[16];
#pragma unroll
        for (int c = 0; c < 16; ++c) {
            int d = d0 + c;
            float xv1 = X[r][d] * sc * wn[d];
            float xv2 = X[r][d + 64] * sc * wn[d + 64];
            o1v[c] = xv1 * cosb[t * HD + d] - xv2 * sinb[t * HD + d];
            o2v[c] = xv2 * cosb[t * HD + d + 64] + xv1 * sinb[t * HD + d + 64];
        }
        f16x8 w0, w1, w2, w3;
#pragma unroll
        for (int c = 0; c < 8; ++c) {
            w0[c] = (f16_t)o1v[c];     w1[c] = (f16_t)o1v[8 + c];
            w2[c] = (f16_t)o2v[c];     w3[c] = (f16_t)o2v[8 + c];
        }
        f16_t* o = (isq ? qf : kf) + ((size_t)slot * SEQ + t) * HD;
        *(f16x8*)(o + d0) = w0;
        *(f16x8*)(o + d0 + 8) = w1;
        *(f16x8*)(o + d0 + 64) = w2;
        *(f16x8*)(o + d0 + 72) = w3;
    } else {
        int kvh = bn - 24;
#pragma unroll
        for (int it = 0; it < 4; ++it) {
            int task = it * 256 + tid;
            int d = task >> 3, seg = task & 7;
            f16x8 o;
#pragma unroll
            for (int j = 0; j < 8; ++j) o[j] = (f16_t)X[seg * 8 + j][d];
            *(f16x8*)(vT + ((size_t)kvh * HD + d) * SEQ + t0 + seg * 8) = o;
        }
    }
}

// ---------------------------------------------------------------------------
// wo GEMM -> bf16 split-K partials, plus distributed conv blocks
__global__ __launch_bounds__(256) void g_wo(
    const char* A, const char* B, bf16_t* parts,
    const float* Wq, const float* Wk, const float* Wv, const float* Wo,
    const float* Wg, const float* Wu, const float* Wd,
    int lnext, char* imgnext)
{
    __shared__ __align__(128) char smem[49152];
    if (blockIdx.x >= 256) {
        conv_tile(blockIdx.x - 256 + 960, lnext, Wq, Wk, Wv, Wo, Wg, Wu, Wd, imgnext, smem);
        return;
    }
    f32x4 acc[2][4];
    int bm, bn, s;
    gemm_loop<8, 4, 32>(A, B, smem, blockIdx.x, acc, bm, bn, s);
    int tid = threadIdx.x;
    int wv = tid >> 6, l = tid & 63, lg = l >> 4, lr = l & 15;
    int wr = wv >> 1, wc = wv & 1;
    bf16_t* P = parts + (size_t)s * 524288;
#pragma unroll
    for (int i = 0; i < 2; ++i)
#pragma unroll
        for (int j = 0; j < 4; ++j)
#pragma unroll
            for (int ii = 0; ii < 4; ++ii) {
                int row = bm * 64 + wr * 32 + i * 16 + lg * 4 + ii;
                int col = bn * 128 + wc * 64 + j * 16 + lr;
                P[(size_t)row * 1024 + col] = (bf16_t)acc[i][j][ii];
            }
}

// gu GEMM with fused swiglu -> mimg, plus distributed conv blocks
__global__ __launch_bounds__(256) void g_gu(
    const char* A, const char* B, char* mimg,
    const float* Wq, const float* Wk, const float* Wv, const float* Wo,
    const float* Wg, const float* Wu, const float* Wd,
    int lnext, char* imgnext)
{
    __shared__ __align__(128) char smem[49152];
    if (blockIdx.x >= 384) {
        conv_tile(blockIdx.x - 384 + 1920, lnext, Wq, Wk, Wv, Wo, Wg, Wu, Wd, imgnext, smem);
        return;
    }
    f32x4 acc[2][4];
    int bm, bn, s;
    gemm_loop<48, 1, 16>(A, B, smem, blockIdx.x, acc, bm, bn, s);
    int tid = threadIdx.x;
    int wv = tid >> 6, l = tid & 63, lg = l >> 4, lr = l & 15;
    int wr = wv >> 1, wc = wv & 1;
#pragma unroll
    for (int i = 0; i < 2; ++i)
#pragma unroll
        for (int jp = 0; jp < 2; ++jp)
#pragma unroll
            for (int ii = 0; ii < 4; ++ii) {
                int row = bm * 64 + wr * 32 + i * 16 + lg * 4 + ii;
                int col = (bn * 2 + wc) * 32 + jp * 16 + lr;
                float gv = acc[i][2 * jp][ii];
                float uv = acc[i][2 * jp + 1][ii];
                float val = gv / (1.f + __expf(-gv)) * uv;
                *(bf16_t*)(mimg + aoff(row, col, 48)) = (bf16_t)val;
            }
}

// wd GEMM + final conv chunk
__global__ __launch_bounds__(256) void k_wdc(
    const char* A, const char* B, bf16_t* parts,
    const float* Wq, const float* Wk, const float* Wv, const float* Wo,
    const float* Wg, const float* Wu, const float* Wd,
    int lnext, char* imgnext)
{
    __shared__ __align__(128) char smem[49152];
    int b = blockIdx.x;
    if (b >= 256) {
        conv_tile(b - 256 + 2880, lnext, Wq, Wk, Wv, Wo, Wg, Wu, Wd, imgnext, smem);
        return;
    }
    f32x4 acc[2][4];
    int bm, bn, s;
    gemm_loop<8, 4, 48>(A, B, smem, b, acc, bm, bn, s);
    int tid = threadIdx.x;
    int wv = tid >> 6, l = tid & 63, lg = l >> 4, lr = l & 15;
    int wr = wv >> 1, wc = wv & 1;
    bf16_t* P = parts + (size_t)s * 524288;
#pragma unroll
    for (int i = 0; i < 2; ++i)
#pragma unroll
        for (int j = 0; j < 4; ++j)
#pragma unroll
            for (int ii = 0; ii < 4; ++ii) {
                int row = bm * 64 + wr * 32 + i * 16 + lg * 4 + ii;
                int col = bn * 128 + wc * 64 + j * 16 + lr;
                P[(size_t)row * 1024 + col] = (bf16_t)acc[i][j][ii];
            }
}

// ---------------------------------------------------------------------------
// causal flash attention -> attn-out image; heavy q-tiles launched first.
__global__ __launch_bounds__(128) void k_attn(
    const f16_t* __restrict__ qf, const f16_t* __restrict__ kf,
    const f16_t* __restrict__ vT, char* __restrict__ attimg)
{
    int h = blockIdx.x >> 4, qb = 15 - (blockIdx.x & 15);
    int kvh = h >> 1;
    __shared__ f16_t Kt[64][136];
    __shared__ f16_t Vt[128][72];
    __shared__ f16_t Pl[2][16][72];
    int tid = threadIdx.x;
    int wv = tid >> 6, l = tid & 63, lg = l >> 4, lr = l & 15;
    int q0 = qb * 32;
    int qrow = q0 + wv * 16;

    f16x8 aq[4];
    const f16_t* qp = qf + ((size_t)h * SEQ + qrow + lr) * HD;
#pragma unroll
    for (int c = 0; c < 4; ++c) aq[c] = *(const f16x8*)(qp + c * 32 + lg * 8);

    f32x4 accv[8];
#pragma unroll
    for (int df = 0; df < 8; ++df) { f32x4 z = {0.f, 0.f, 0.f, 0.f}; accv[df] = z; }
    float mrun[4], lrun[4];
#pragma unroll
    for (int ii = 0; ii < 4; ++ii) { mrun[ii] = -3e38f; lrun[ii] = 0.f; }

    int ktiles = (q0 + 32 + 63) >> 6;
    for (int kt = 0; kt < ktiles; ++kt) {
        int kt0 = kt * 64;
        __syncthreads();
#pragma unroll
        for (int it = 0; it < 8; ++it) {
            int idx = it * 128 + tid;
            int r = idx >> 4, seg = idx & 15;
            *(int4*)&Kt[r][seg * 8] =
                *(const int4*)(kf + ((size_t)kvh * SEQ + kt0 + r) * HD + seg * 8);
        }
#pragma unroll
        for (int it = 0; it < 8; ++it) {
            int idx = it * 128 + tid;
            int r = idx >> 3, seg = idx & 7;
            *(int4*)&Vt[r][seg * 8] =
                *(const int4*)(vT + ((size_t)kvh * HD + r) * SEQ + kt0 + seg * 8);
        }
        __syncthreads();

        f32x4 s[4];
#pragma unroll
        for (int nf = 0; nf < 4; ++nf) {
            f32x4 a = {0.f, 0.f, 0.f, 0.f};
#pragma unroll
            for (int c = 0; c < 4; ++c) {
                f16x8 bk = *(const f16x8*)&Kt[nf * 16 + lr][c * 32 + lg * 8];
                a = __builtin_amdgcn_mfma_f32_16x16x32_f16(aq[c], bk, a, 0, 0, 0);
            }
            s[nf] = a;
        }
        const float scale = 0.08838834764831845f;
        float tmax[4] = {-3e38f, -3e38f, -3e38f, -3e38f};
#pragma unroll
        for (int nf = 0; nf < 4; ++nf) {
            int ktg = kt0 + nf * 16 + lr;
#pragma unroll
            for (int ii = 0; ii < 4; ++ii) {
                int qg = qrow + lg * 4 + ii;
                float vv = s[nf][ii] * scale;
                vv = (ktg <= qg) ? vv : -1e30f;
                s[nf][ii] = vv;
                tmax[ii] = fmaxf(tmax[ii], vv);
            }
        }
#pragma unroll
        for (int m = 1; m < 16; m <<= 1)
#pragma unroll
            for (int ii = 0; ii < 4; ++ii)
                tmax[ii] = fmaxf(tmax[ii], __shfl_xor(tmax[ii], m));
        float corr[4];
#pragma unroll
        for (int ii = 0; ii < 4; ++ii) {
            float mnew = fmaxf(mrun[ii], tmax[ii]);
            corr[ii] = __expf(mrun[ii] - mnew);
            mrun[ii] = mnew;
        }
        float tsum[4] = {0.f, 0.f, 0.f, 0.f};
#pragma unroll
        for (int nf = 0; nf < 4; ++nf)
#pragma unroll
            for (int ii = 0; ii < 4; ++ii) {
                float pp = __expf(s[nf][ii] - mrun[ii]);
                s[nf][ii] = pp;
                tsum[ii] += pp;
            }
#pragma unroll
        for (int m = 1; m < 16; m <<= 1)
#pragma unroll
            for (int ii = 0; ii < 4; ++ii) tsum[ii] += __shfl_xor(tsum[ii], m);
#pragma unroll
        for (int ii = 0; ii < 4; ++ii) lrun[ii] = lrun[ii] * corr[ii] + tsum[ii];
#pragma unroll
        for (int df = 0; df < 8; ++df)
#pragma unroll
            for (int ii = 0; ii < 4; ++ii) accv[df][ii] *= corr[ii];
#pragma unroll
        for (int nf = 0; nf < 4; ++nf)
#pragma unroll
            for (int ii = 0; ii < 4; ++ii)
                Pl[wv][lg * 4 + ii][nf * 16 + lr] = (f16_t)s[nf][ii];
        __syncthreads();
#pragma unroll
        for (int c = 0; c < 2; ++c) {
            f16x8 ap = *(const f16x8*)&Pl[wv][lr][c * 32 + lg * 8];
#pragma unroll
            for (int df = 0; df < 8; ++df) {
                f16x8 bv = *(const f16x8*)&Vt[df * 16 + lr][c * 32 + lg * 8];
                accv[df] = __builtin_amdgcn_mfma_f32_16x16x32_f16(ap, bv, accv[df], 0, 0, 0);
            }
        }
    }
#pragma unroll
    for (int df = 0; df < 8; ++df)
#pragma unroll
        for (int ii = 0; ii < 4; ++ii) {
            int qg = qrow + lg * 4 + ii;
            int col = h * HD + df * 16 + lr;
            *(bf16_t*)(attimg + aoff(qg, col, 32)) =
                (bf16_t)(accv[df][ii] / lrun[ii]);
        }
}

// ---------------------------------------------------------------------------
extern "C" void kernel_launch(void* const* d_in, const int* in_sizes, int n_in,
                              void* d_out, int out_size, void* d_ws, size_t ws_size,
                              hipStream_t stream)
{
    const float* hin  = (const float*)d_in[0];
    const float* cosb = (const float*)d_in[1];
    const float* sinb = (const float*)d_in[2];
    const float* Wq = (const float*)d_in[4];
    const float* Wk = (const float*)d_in[5];
    const float* Wv = (const float*)d_in[6];
    const float* Wo = (const float*)d_in[7];
    const float* Wg = (const float*)d_in[8];
    const float* Wu = (const float*)d_in[9];
    const float* Wd = (const float*)d_in[10];
    const float* Ln1 = (const float*)d_in[11];
    const float* Ln2 = (const float*)d_in[12];
    const float* Qn = (const float*)d_in[13];
    const float* Kn = (const float*)d_in[14];

    char* p = (char*)d_ws;
    auto alloc = [&](size_t bytes) { char* r = p; p += bytes; return r; };
    float*  h     = (float*)alloc(2097152);
    bf16_t* parts = (bf16_t*)alloc(4194304);
    char*   ximg  = alloc(1048576);
    char*   yimg  = alloc(1048576);
    char*   attimg= alloc(2097152);
    char*   mimg  = alloc(3145728);
    f16_t*  qf    = (f16_t*)alloc(2097152);
    f16_t*  kf    = (f16_t*)alloc(1048576);
    f16_t*  vT    = (f16_t*)alloc(1048576);
    char*   imgA  = alloc(IMG_LAYER_BYTES);
    size_t fixed = (size_t)(imgA + IMG_LAYER_BYTES - (char*)d_ws);
    bool pp = ws_size >= fixed + IMG_LAYER_BYTES;
    char* imgB = pp ? alloc(IMG_LAYER_BYTES) : imgA;

    k_copy<<<512, 256, 0, stream>>>(hin, h);
    k_conv<<<3840, 256, 0, stream>>>(0, Wq, Wk, Wv, Wo, Wg, Wu, Wd, imgA);

    for (int l = 0; l < 28; ++l) {
        char* img  = (l & 1) ? imgB : imgA;
        char* imgn = (l & 1) ? imgA : imgB;
        bool cv = pp && (l < 27);
        int ln = l + 1;

        k_rms<<<512, 256, 0, stream>>>(h, parts, l == 0 ? 0 : 4,
                                       Ln1 + (size_t)l * 1024, ximg);
        g_qkvf<<<cv ? 1216 : 256, 256, 0, stream>>>(
            ximg, img + IMG_QKV, cosb, sinb,
            Qn + (size_t)l * 128, Kn + (size_t)l * 128, qf, kf, vT,
            Wq, Wk, Wv, Wo, Wg, Wu, Wd, ln, imgn);
        k_attn<<<256, 128, 0, stream>>>(qf, kf, vT, attimg);
        g_wo<<<cv ? 1216 : 256, 256, 0, stream>>>(
            attimg, img + IMG_WO, parts,
            Wq, Wk, Wv, Wo, Wg, Wu, Wd, ln, imgn);
        k_rms<<<512, 256, 0, stream>>>(h, parts, 4, Ln2 + (size_t)l * 1024, yimg);
        g_gu<<<cv ? 1536 : 384, 256, 0, stream>>>(
            yimg, img + IMG_GU, mimg,
            Wq, Wk, Wv, Wo, Wg, Wu, Wd, ln, imgn);
        k_wdc<<<cv ? 1216 : 256, 256, 0, stream>>>(
            mimg, img + IMG_WD, parts,
            Wq, Wk, Wv, Wo, Wg, Wu, Wd, ln, imgn);
        if (!pp && l < 27)
            k_conv<<<3840, 256, 0, stream>>>(ln, Wq, Wk, Wv, Wo, Wg, Wu, Wd, imgA);
    }
    k_finalize<<<512, 256, 0, stream>>>(h, parts, (float*)d_out);
}